// Round 2
// baseline (1237.141 us; speedup 1.0000x reference)
//
#include <hip/hip_runtime.h>

#define N_NODES 50000
#define N_EDGES 400000
#define M_PAD   50048   // 391 * 128
#define EPS_BN  1e-5f

typedef short bf16x8 __attribute__((ext_vector_type(8)));
typedef float f32x4 __attribute__((ext_vector_type(4)));

__device__ __forceinline__ float bf2f(unsigned short h) {
  union { unsigned int u; float f; } v; v.u = ((unsigned int)h) << 16; return v.f;
}
__device__ __forceinline__ unsigned short f2bf(float x) {
  union { float f; unsigned int u; } v; v.f = x;
  unsigned int r = v.u + 0x7FFFu + ((v.u >> 16) & 1u);
  return (unsigned short)(r >> 16);
}

// ---------------- CSR build ----------------
__global__ void count_deg(const int* __restrict__ dst, int* __restrict__ deg) {
  int e = blockIdx.x * 256 + threadIdx.x;
  if (e < N_EDGES) {
    int d = dst[e];
    if (d >= 0 && d < N_NODES) atomicAdd(&deg[d], 1);
  }
}

__global__ void scan_kernel(const int* __restrict__ deg, int* __restrict__ row_ptr,
                            int* __restrict__ cursor) {
  __shared__ int sdata[1024];
  const int t = threadIdx.x;
  const int CH = (N_NODES + 1023) / 1024;  // 49
  const int base = t * CH;
  int s = 0;
  for (int i = 0; i < CH; ++i) {
    int idx = base + i;
    if (idx < N_NODES) s += deg[idx];
  }
  sdata[t] = s;
  __syncthreads();
  for (int off = 1; off < 1024; off <<= 1) {
    int add = (t >= off) ? sdata[t - off] : 0;
    __syncthreads();
    sdata[t] += add;
    __syncthreads();
  }
  int run = (t == 0) ? 0 : sdata[t - 1];
  for (int i = 0; i < CH; ++i) {
    int idx = base + i;
    if (idx < N_NODES) {
      row_ptr[idx] = run;
      cursor[idx]  = run;
      run += deg[idx];
    }
  }
  if (t == 1023) row_ptr[N_NODES] = sdata[1023];
}

__global__ void scatter_edges(const int* __restrict__ src, const int* __restrict__ dst,
                              int* __restrict__ cursor, int* __restrict__ esrc) {
  int e = blockIdx.x * 256 + threadIdx.x;
  if (e < N_EDGES) {
    int d = dst[e];
    int s = src[e];
    if (d >= 0 && d < N_NODES && s >= 0 && s < N_NODES) {
      int p = atomicAdd(&cursor[d], 1);
      esrc[p] = s;
    }
  }
}

// ---------------- weight pack: [Wl;Wr] transposed to [Npad][Kpad] bf16 ----------------
__global__ void pack_wt(const float* __restrict__ Wl, const float* __restrict__ Wr,
                        unsigned short* __restrict__ WT, int Keach, int N, int Npad, int Kpad) {
  int idx = blockIdx.x * 256 + threadIdx.x;
  if (idx >= Npad * Kpad) return;
  int n = idx / Kpad, k = idx % Kpad;
  float v = 0.f;
  if (n < N) {
    if (k < Keach) v = Wl[k * N + n];
    else if (k < 2 * Keach) v = Wr[(k - Keach) * N + n];
  }
  WT[idx] = f2bf(v);
}

// ---------------- layer-1 input build: cat1[n] = [agg(x) | x | 0pad] (128 cols bf16) ----------------
__global__ void prep1(const float* __restrict__ x, const int* __restrict__ row_ptr,
                      const int* __restrict__ esrc, unsigned short* __restrict__ cat1) {
  int n = blockIdx.x, t = threadIdx.x;
  unsigned short* row = cat1 + (long)n * 128;
  if (n >= N_NODES) { row[t] = 0; row[64 + t] = 0; return; }
  int e0 = row_ptr[n], e1 = row_ptr[n + 1];
  if (t < 50) {
    float acc = 0.f;
    for (int e = e0; e < e1; ++e) acc += x[(long)esrc[e] * 50 + t];
    float rdeg = (e1 > e0) ? 1.f / (float)(e1 - e0) : 0.f;
    row[t]      = f2bf(acc * rdeg);
    row[50 + t] = f2bf(x[(long)n * 50 + t]);
  }
  if (t >= 36) row[64 + t] = 0;  // cols 100..127 = 0
}

// ---------------- mean aggregation: agg[n][f] = mean over in-edges of h[src][f] ----------------
__global__ void agg_mean(const int* __restrict__ row_ptr, const int* __restrict__ esrc,
                         const unsigned short* __restrict__ h, unsigned short* __restrict__ agg) {
  int n = blockIdx.x, f = threadIdx.x;
  unsigned short* out = agg + (long)n * 512 + f;
  if (n >= N_NODES) { *out = 0; return; }
  int e0 = row_ptr[n], e1 = row_ptr[n + 1];
  float acc = 0.f;
  for (int e = e0; e < e1; ++e) {
    int s = esrc[e];
    acc += bf2f(h[(long)s * 512 + f]);
  }
  float rdeg = (e1 > e0) ? 1.f / (float)(e1 - e0) : 0.f;
  *out = f2bf(acc * rdeg);
}

// ---------------- BN stats / finalize / apply+ReLU ----------------
__global__ void bn_stats(const unsigned short* __restrict__ y, float* __restrict__ ssum,
                         float* __restrict__ ssq) {
  int c = blockIdx.x * 128 + (threadIdx.x & 127);
  int r = blockIdx.y * 256 + (threadIdx.x >> 7);
  float s = 0.f, s2 = 0.f;
  for (int i = 0; i < 128; ++i, r += 2) {
    if (r < N_NODES) {
      float v = bf2f(y[(long)r * 512 + c]);
      s += v; s2 += v * v;
    }
  }
  atomicAdd(&ssum[c], s);
  atomicAdd(&ssq[c], s2);
}

__global__ void bn_finalize(const float* __restrict__ ssum, const float* __restrict__ ssq,
                            const float* __restrict__ g, const float* __restrict__ b,
                            float* __restrict__ scale, float* __restrict__ shiftv) {
  int c = threadIdx.x;
  float mu  = ssum[c] * (1.f / N_NODES);
  float var = ssq[c] * (1.f / N_NODES) - mu * mu;
  float rs  = rsqrtf(var + EPS_BN);
  float sc  = g[c] * rs;
  scale[c]  = sc;
  shiftv[c] = b[c] - mu * sc;
}

__global__ void bn_relu(const unsigned short* __restrict__ y, const float* __restrict__ scale,
                        const float* __restrict__ shiftv, unsigned short* __restrict__ hout) {
  long idx = ((long)blockIdx.x * 256 + threadIdx.x) * 8;
  if (idx >= (long)M_PAD * 512) return;
  int row = (int)(idx >> 9);
  int col = (int)(idx & 511);
  unsigned short* o = hout + idx;
  if (row >= N_NODES) {
    uint4 z; z.x = 0; z.y = 0; z.z = 0; z.w = 0;
    *(uint4*)o = z;
    return;
  }
  uint4 v = *(const uint4*)(y + idx);
  unsigned short* p = (unsigned short*)&v;
  uint4 rr;
  unsigned short* q = (unsigned short*)&rr;
#pragma unroll
  for (int j = 0; j < 8; ++j) {
    float f = bf2f(p[j]) * scale[col + j] + shiftv[col + j];
    q[j] = f2bf(fmaxf(f, 0.f));
  }
  *(uint4*)o = rr;
}

// ---------------- bf16 MFMA GEMM: C = [A0|A1][M][K] @ B (given as BT[N][K]) + bias ----------------
__device__ __forceinline__ void gl_lds16(const void* g, void* l) {
  __builtin_amdgcn_global_load_lds((const __attribute__((address_space(1))) unsigned int*)g,
                                   (__attribute__((address_space(3))) unsigned int*)l, 16, 0, 0);
}

template <int FINAL>
__global__ void gemm_bf16(const unsigned short* __restrict__ A0,
                          const unsigned short* __restrict__ A1, int lda, int KA0,
                          const unsigned short* __restrict__ BT, int K,
                          const float* __restrict__ bias, void* __restrict__ outp, int ldo,
                          int Mv, int Nv) {
  __shared__ __align__(16) unsigned short As[128 * 64];
  __shared__ __align__(16) unsigned short Bs[128 * 64];
  const int t    = threadIdx.x;
  const int lane = t & 63;
  const int wave = t >> 6;
  const long brow = (long)blockIdx.x * 128;
  const int  bcol = blockIdx.y * 128;
  const int  wr   = (wave >> 1) * 64;
  const int  wc   = (wave & 1) * 64;

  f32x4 acc[4][4] = {};

  const long aoff = (brow + (t >> 3)) * (long)lda + ((t & 7) * 8);
  const long boff = ((long)(bcol + (t >> 3))) * K + ((t & 7) * 8);
  unsigned short* al0 = As + t * 8;
  unsigned short* bl0 = Bs + t * 8;

  for (int k0 = 0; k0 < K; k0 += 64) {
    const unsigned short* ag = ((k0 < KA0) ? (A0 + k0) : (A1 + (k0 - KA0))) + aoff;
    const unsigned short* bg = BT + boff + k0;
#pragma unroll
    for (int r = 0; r < 4; ++r) {
      gl_lds16(ag + (long)r * 32 * lda, al0 + r * 2048);
      gl_lds16(bg + (long)r * 32 * K, bl0 + r * 2048);
    }
    __syncthreads();
    const unsigned short* ab = As + (wr + (lane & 15)) * 64 + ((lane >> 4) * 8);
    const unsigned short* bb = Bs + (wc + (lane & 15)) * 64 + ((lane >> 4) * 8);
#pragma unroll
    for (int kk = 0; kk < 64; kk += 32) {
      bf16x8 af[4], bfr[4];
#pragma unroll
      for (int m = 0; m < 4; ++m) af[m] = *(const bf16x8*)(ab + m * 16 * 64 + kk);
#pragma unroll
      for (int n = 0; n < 4; ++n) bfr[n] = *(const bf16x8*)(bb + n * 16 * 64 + kk);
#pragma unroll
      for (int m = 0; m < 4; ++m)
#pragma unroll
        for (int n = 0; n < 4; ++n)
          acc[m][n] = __builtin_amdgcn_mfma_f32_16x16x32_bf16(af[m], bfr[n], acc[m][n], 0, 0, 0);
    }
    __syncthreads();
  }

#pragma unroll
  for (int m = 0; m < 4; ++m) {
    int row0 = (int)brow + wr + m * 16 + (lane >> 4) * 4;
#pragma unroll
    for (int n = 0; n < 4; ++n) {
      int col = bcol + wc + n * 16 + (lane & 15);
      if (FINAL) {
        if (col < Nv) {
          float bs = bias[col];
#pragma unroll
          for (int j = 0; j < 4; ++j) {
            int row = row0 + j;
            if (row < Mv) ((float*)outp)[(long)row * ldo + col] = acc[m][n][j] + bs;
          }
        }
      } else {
        float bs = bias[col];
        unsigned short* o = (unsigned short*)outp;
#pragma unroll
        for (int j = 0; j < 4; ++j) o[(long)(row0 + j) * ldo + col] = f2bf(acc[m][n][j] + bs);
      }
    }
  }
}

// ---------------- host launcher ----------------
extern "C" void kernel_launch(void* const* d_in, const int* in_sizes, int n_in, void* d_out,
                              int out_size, void* d_ws, size_t ws_size, hipStream_t stream) {
  char* p = (char*)d_ws;
  auto take = [&](size_t b) {
    char* r = p;
    p += (b + 255) & ~(size_t)255;
    return r;
  };
  int* deg      = (int*)take((size_t)N_NODES * 4);
  int* row_ptr  = (int*)take((size_t)(N_NODES + 4) * 4);
  int* cursor   = (int*)take((size_t)N_NODES * 4);
  int* esrc     = (int*)take((size_t)N_EDGES * 4);
  unsigned short* W1T = (unsigned short*)take((size_t)512 * 128 * 2);
  unsigned short* W2T = (unsigned short*)take((size_t)512 * 1024 * 2);
  unsigned short* W3T = (unsigned short*)take((size_t)512 * 1024 * 2);
  unsigned short* W4T = (unsigned short*)take((size_t)128 * 1024 * 2);
  float* ssum   = (float*)take(512 * 4);
  float* ssq    = (float*)take(512 * 4);
  float* scale  = (float*)take(512 * 4);
  float* shiftv = (float*)take(512 * 4);
  unsigned short* abuf = (unsigned short*)take((size_t)M_PAD * 512 * 2);  // agg / cat1
  unsigned short* ybuf = (unsigned short*)take((size_t)M_PAD * 512 * 2);  // pre-BN GEMM out
  unsigned short* hbuf = (unsigned short*)take((size_t)M_PAD * 512 * 2);  // activations

  // Workspace guard: if insufficient, fail readably (zero output) instead of corrupting memory.
  size_t need = (size_t)(p - (char*)d_ws);
  if (need > ws_size || n_in < 20) {
    hipMemsetAsync(d_out, 0, (size_t)out_size * 4, stream);
    return;
  }

  const float* x   = (const float*)d_in[0];
  const int*   ei  = (const int*)d_in[1];
  const int*   srcv = ei;
  const int*   dstv = ei + N_EDGES;
  const float* Wl1 = (const float*)d_in[2];
  const float* bl1 = (const float*)d_in[3];
  const float* Wr1 = (const float*)d_in[4];
  const float* Wl2 = (const float*)d_in[5];
  const float* bl2 = (const float*)d_in[6];
  const float* Wr2 = (const float*)d_in[7];
  const float* Wl3 = (const float*)d_in[8];
  const float* bl3 = (const float*)d_in[9];
  const float* Wr3 = (const float*)d_in[10];
  const float* Wl4 = (const float*)d_in[11];
  const float* bl4 = (const float*)d_in[12];
  const float* Wr4 = (const float*)d_in[13];
  const float* g1  = (const float*)d_in[14];
  const float* b1  = (const float*)d_in[15];
  const float* g2  = (const float*)d_in[16];
  const float* b2  = (const float*)d_in[17];
  const float* g3  = (const float*)d_in[18];
  const float* b3  = (const float*)d_in[19];

  // CSR
  hipMemsetAsync(deg, 0, (size_t)N_NODES * 4, stream);
  count_deg<<<(N_EDGES + 255) / 256, 256, 0, stream>>>(dstv, deg);
  scan_kernel<<<1, 1024, 0, stream>>>(deg, row_ptr, cursor);
  scatter_edges<<<(N_EDGES + 255) / 256, 256, 0, stream>>>(srcv, dstv, cursor, esrc);

  // weights
  pack_wt<<<(512 * 128 + 255) / 256, 256, 0, stream>>>(Wl1, Wr1, W1T, 50, 512, 512, 128);
  pack_wt<<<(512 * 1024 + 255) / 256, 256, 0, stream>>>(Wl2, Wr2, W2T, 512, 512, 512, 1024);
  pack_wt<<<(512 * 1024 + 255) / 256, 256, 0, stream>>>(Wl3, Wr3, W3T, 512, 512, 512, 1024);
  pack_wt<<<(128 * 1024 + 255) / 256, 256, 0, stream>>>(Wl4, Wr4, W4T, 512, 121, 128, 1024);

  dim3 gemm_grid(391, 4);
  int bn_blocks = (int)(((long)M_PAD * 512 / 8) / 256);

  // ---- layer 1 ----
  prep1<<<M_PAD, 64, 0, stream>>>(x, row_ptr, esrc, abuf);
  gemm_bf16<0><<<gemm_grid, 256, 0, stream>>>(abuf, abuf, 128, 128, W1T, 128, bl1, ybuf, 512,
                                              M_PAD, 512);
  hipMemsetAsync(ssum, 0, 512 * 4, stream);
  hipMemsetAsync(ssq, 0, 512 * 4, stream);
  bn_stats<<<dim3(4, 196), 256, 0, stream>>>(ybuf, ssum, ssq);
  bn_finalize<<<1, 512, 0, stream>>>(ssum, ssq, g1, b1, scale, shiftv);
  bn_relu<<<bn_blocks, 256, 0, stream>>>(ybuf, scale, shiftv, hbuf);

  // ---- layer 2 ----
  agg_mean<<<M_PAD, 512, 0, stream>>>(row_ptr, esrc, hbuf, abuf);
  gemm_bf16<0><<<gemm_grid, 256, 0, stream>>>(abuf, hbuf, 512, 512, W2T, 1024, bl2, ybuf, 512,
                                              M_PAD, 512);
  hipMemsetAsync(ssum, 0, 512 * 4, stream);
  hipMemsetAsync(ssq, 0, 512 * 4, stream);
  bn_stats<<<dim3(4, 196), 256, 0, stream>>>(ybuf, ssum, ssq);
  bn_finalize<<<1, 512, 0, stream>>>(ssum, ssq, g2, b2, scale, shiftv);
  bn_relu<<<bn_blocks, 256, 0, stream>>>(ybuf, scale, shiftv, hbuf);

  // ---- layer 3 ----
  agg_mean<<<M_PAD, 512, 0, stream>>>(row_ptr, esrc, hbuf, abuf);
  gemm_bf16<0><<<gemm_grid, 256, 0, stream>>>(abuf, hbuf, 512, 512, W3T, 1024, bl3, ybuf, 512,
                                              M_PAD, 512);
  hipMemsetAsync(ssum, 0, 512 * 4, stream);
  hipMemsetAsync(ssq, 0, 512 * 4, stream);
  bn_stats<<<dim3(4, 196), 256, 0, stream>>>(ybuf, ssum, ssq);
  bn_finalize<<<1, 512, 0, stream>>>(ssum, ssq, g3, b3, scale, shiftv);
  bn_relu<<<bn_blocks, 256, 0, stream>>>(ybuf, scale, shiftv, hbuf);

  // ---- layer 4 (no BN, fp32 out) ----
  agg_mean<<<M_PAD, 512, 0, stream>>>(row_ptr, esrc, hbuf, abuf);
  gemm_bf16<1><<<dim3(391, 1), 256, 0, stream>>>(abuf, hbuf, 512, 512, W4T, 1024, bl4, d_out, 121,
                                                 N_NODES, 121);
}

// Round 4
// 933.686 us; speedup vs baseline: 1.3250x; 1.3250x over previous
//
#include <hip/hip_runtime.h>

#define N_NODES 50000
#define N_EDGES 400000
#define M_PAD   50048   // 391 * 128
#define EPS_BN  1e-5f

typedef short bf16x8 __attribute__((ext_vector_type(8)));
typedef float f32x4 __attribute__((ext_vector_type(4)));

__device__ __forceinline__ float bf2f(unsigned short h) {
  union { unsigned int u; float f; } v; v.u = ((unsigned int)h) << 16; return v.f;
}
__device__ __forceinline__ unsigned short f2bf(float x) {
  union { float f; unsigned int u; } v; v.f = x;
  unsigned int r = v.u + 0x7FFFu + ((v.u >> 16) & 1u);
  return (unsigned short)(r >> 16);
}

// ---------------- CSR build ----------------
__global__ void count_deg(const int* __restrict__ dst, int* __restrict__ deg) {
  int e = blockIdx.x * 256 + threadIdx.x;
  if (e < N_EDGES) {
    int d = dst[e];
    if (d >= 0 && d < N_NODES) atomicAdd(&deg[d], 1);
  }
}

__global__ void scan_kernel(const int* __restrict__ deg, int* __restrict__ row_ptr,
                            int* __restrict__ cursor) {
  __shared__ int sdata[1024];
  const int t = threadIdx.x;
  const int CH = (N_NODES + 1023) / 1024;  // 49
  const int base = t * CH;
  int s = 0;
  for (int i = 0; i < CH; ++i) {
    int idx = base + i;
    if (idx < N_NODES) s += deg[idx];
  }
  sdata[t] = s;
  __syncthreads();
  for (int off = 1; off < 1024; off <<= 1) {
    int add = (t >= off) ? sdata[t - off] : 0;
    __syncthreads();
    sdata[t] += add;
    __syncthreads();
  }
  int run = (t == 0) ? 0 : sdata[t - 1];
  for (int i = 0; i < CH; ++i) {
    int idx = base + i;
    if (idx < N_NODES) {
      row_ptr[idx] = run;
      cursor[idx]  = run;
      run += deg[idx];
    }
  }
  if (t == 1023) row_ptr[N_NODES] = sdata[1023];
}

__global__ void scatter_edges(const int* __restrict__ src, const int* __restrict__ dst,
                              int* __restrict__ cursor, int* __restrict__ esrc) {
  int e = blockIdx.x * 256 + threadIdx.x;
  if (e < N_EDGES) {
    int d = dst[e];
    int s = src[e];
    if (d >= 0 && d < N_NODES && s >= 0 && s < N_NODES) {
      int p = atomicAdd(&cursor[d], 1);
      esrc[p] = s;
    }
  }
}

// ---------------- weight packs ----------------
// [Wl;Wr] concat transposed to [Npad][Kpad] bf16
__global__ void pack_wt(const float* __restrict__ Wl, const float* __restrict__ Wr,
                        unsigned short* __restrict__ WT, int Keach, int N, int Npad, int Kpad) {
  int idx = blockIdx.x * 256 + threadIdx.x;
  if (idx >= Npad * Kpad) return;
  int n = idx / Kpad, k = idx % Kpad;
  float v = 0.f;
  if (n < N) {
    if (k < Keach) v = Wl[k * N + n];
    else if (k < 2 * Keach) v = Wr[(k - Keach) * N + n];
  }
  WT[idx] = f2bf(v);
}

// single matrix W[K][N] -> WT[Npad][Kpad] bf16
__global__ void pack_w1(const float* __restrict__ W, unsigned short* __restrict__ WT, int K,
                        int N, int Npad, int Kpad) {
  int idx = blockIdx.x * 256 + threadIdx.x;
  if (idx >= Npad * Kpad) return;
  int n = idx / Kpad, k = idx % Kpad;
  float v = (n < N && k < K) ? W[k * N + n] : 0.f;
  WT[idx] = f2bf(v);
}

// ---------------- layer-1 input build: cat1[n] = [agg(x) | x | 0pad] (128 cols bf16) ----------
__global__ void prep1v(const float* __restrict__ x, const int* __restrict__ row_ptr,
                       const int* __restrict__ esrc, unsigned short* __restrict__ cat1) {
  __shared__ float part[4][64];
  int n = blockIdx.x, t = threadIdx.x;
  int w = t >> 6, lane = t & 63;
  unsigned short* row = cat1 + (long)n * 128;
  if (n >= N_NODES) {
    if (t < 64) { row[t] = 0; row[64 + t] = 0; }
    return;
  }
  int e0 = row_ptr[n], e1 = row_ptr[n + 1];
  float acc = 0.f;
  if (lane < 50) {
    for (int e = e0 + w; e < e1; e += 4) acc += x[(long)esrc[e] * 50 + lane];
  }
  part[w][lane] = acc;
  __syncthreads();
  if (t < 128) {
    if (t < 64) {
      float s = part[0][t] + part[1][t] + part[2][t] + part[3][t];
      float rdeg = (e1 > e0) ? 1.f / (float)(e1 - e0) : 0.f;
      if (t < 50) {
        row[t]      = f2bf(s * rdeg);
        row[50 + t] = f2bf(x[(long)n * 50 + t]);
      }
    } else if (t >= 100) {
      row[t] = 0;  // cols 100..127
    }
  }
}

// ---------------- mean aggregation, 512 cols: wave-per-edge vectorized gather -------------
__global__ void agg_mean512(const int* __restrict__ row_ptr, const int* __restrict__ esrc,
                            const unsigned short* __restrict__ h,
                            unsigned short* __restrict__ agg) {
  __shared__ float part[4][512];
  int n = blockIdx.x, t = threadIdx.x;
  int w = t >> 6, lane = t & 63;
  unsigned int* outw = (unsigned int*)(agg + (long)n * 512);
  if (n >= N_NODES) { outw[t] = 0; return; }
  int e0 = row_ptr[n], e1 = row_ptr[n + 1];
  float acc[8] = {0.f, 0.f, 0.f, 0.f, 0.f, 0.f, 0.f, 0.f};
  for (int e = e0 + w; e < e1; e += 4) {
    int s = esrc[e];
    uint4 v = *(const uint4*)(h + (long)s * 512 + lane * 8);
    const unsigned short* pv = (const unsigned short*)&v;
#pragma unroll
    for (int j = 0; j < 8; ++j) acc[j] += bf2f(pv[j]);
  }
  float* pw = &part[w][lane * 8];
#pragma unroll
  for (int j = 0; j < 8; ++j) pw[j] = acc[j];
  __syncthreads();
  int c = t * 2;
  float s0 = part[0][c] + part[1][c] + part[2][c] + part[3][c];
  float s1 = part[0][c + 1] + part[1][c + 1] + part[2][c + 1] + part[3][c + 1];
  float rdeg = (e1 > e0) ? 1.f / (float)(e1 - e0) : 0.f;
  unsigned int pk = (unsigned int)f2bf(s0 * rdeg) | ((unsigned int)f2bf(s1 * rdeg) << 16);
  outw[t] = pk;
}

// ---------------- layer-4 gather-add: out[n][c] += mean over edges of t4[src][c], 121 cols ----
__global__ void agg_add121(const int* __restrict__ row_ptr, const int* __restrict__ esrc,
                           const unsigned short* __restrict__ t4, float* __restrict__ out) {
  int n = blockIdx.x * 4 + (threadIdx.x >> 6);
  if (n >= N_NODES) return;
  int lane = threadIdx.x & 63;
  int g = lane >> 4;    // edge group 0..3
  int cl = lane & 15;   // col group: cols cl*8..cl*8+7
  int e0 = row_ptr[n], e1 = row_ptr[n + 1];
  float acc[8] = {0.f, 0.f, 0.f, 0.f, 0.f, 0.f, 0.f, 0.f};
  for (int e = e0 + g; e < e1; e += 4) {
    int s = esrc[e];
    uint4 v = *(const uint4*)(t4 + (long)s * 128 + cl * 8);
    const unsigned short* pv = (const unsigned short*)&v;
#pragma unroll
    for (int j = 0; j < 8; ++j) acc[j] += bf2f(pv[j]);
  }
#pragma unroll
  for (int j = 0; j < 8; ++j) {
    acc[j] += __shfl_xor(acc[j], 16);
    acc[j] += __shfl_xor(acc[j], 32);
  }
  if (g == 0) {
    float rdeg = (e1 > e0) ? 1.f / (float)(e1 - e0) : 0.f;
#pragma unroll
    for (int j = 0; j < 8; ++j) {
      int c = cl * 8 + j;
      if (c < 121) out[(long)n * 121 + c] += acc[j] * rdeg;
    }
  }
}

// ---------------- BN stats / finalize / apply+ReLU ----------------
__global__ void bn_stats(const unsigned short* __restrict__ y, float* __restrict__ ssum,
                         float* __restrict__ ssq) {
  int c = blockIdx.x * 128 + (threadIdx.x & 127);
  int r = blockIdx.y * 256 + (threadIdx.x >> 7);
  float s = 0.f, s2 = 0.f;
  for (int i = 0; i < 128; ++i, r += 2) {
    if (r < N_NODES) {
      float v = bf2f(y[(long)r * 512 + c]);
      s += v; s2 += v * v;
    }
  }
  atomicAdd(&ssum[c], s);
  atomicAdd(&ssq[c], s2);
}

__global__ void bn_finalize(const float* __restrict__ ssum, const float* __restrict__ ssq,
                            const float* __restrict__ g, const float* __restrict__ b,
                            float* __restrict__ scale, float* __restrict__ shiftv) {
  int c = threadIdx.x;
  float mu  = ssum[c] * (1.f / N_NODES);
  float var = ssq[c] * (1.f / N_NODES) - mu * mu;
  float rs  = rsqrtf(var + EPS_BN);
  float sc  = g[c] * rs;
  scale[c]  = sc;
  shiftv[c] = b[c] - mu * sc;
}

__global__ void bn_relu(const unsigned short* __restrict__ y, const float* __restrict__ scale,
                        const float* __restrict__ shiftv, unsigned short* __restrict__ hout) {
  long idx = ((long)blockIdx.x * 256 + threadIdx.x) * 8;
  if (idx >= (long)M_PAD * 512) return;
  int row = (int)(idx >> 9);
  int col = (int)(idx & 511);
  unsigned short* o = hout + idx;
  if (row >= N_NODES) {
    uint4 z; z.x = 0; z.y = 0; z.z = 0; z.w = 0;
    *(uint4*)o = z;
    return;
  }
  uint4 v = *(const uint4*)(y + idx);
  unsigned short* p = (unsigned short*)&v;
  uint4 rr;
  unsigned short* q = (unsigned short*)&rr;
#pragma unroll
  for (int j = 0; j < 8; ++j) {
    float f = bf2f(p[j]) * scale[col + j] + shiftv[col + j];
    q[j] = f2bf(fmaxf(f, 0.f));
  }
  *(uint4*)o = rr;
}

// ---------------- bf16 MFMA GEMM: C = [A0|A1][M][K] @ B (given as BT[N][K]) + bias ----------
__device__ __forceinline__ void gl_lds16(const void* g, void* l) {
  __builtin_amdgcn_global_load_lds((const __attribute__((address_space(1))) unsigned int*)g,
                                   (__attribute__((address_space(3))) unsigned int*)l, 16, 0, 0);
}

template <int FINAL>
__global__ void gemm_bf16(const unsigned short* __restrict__ A0,
                          const unsigned short* __restrict__ A1, int lda, int KA0,
                          const unsigned short* __restrict__ BT, int K,
                          const float* __restrict__ bias, void* __restrict__ outp, int ldo,
                          int Mv, int Nv) {
  __shared__ __align__(16) unsigned short As[128 * 64];
  __shared__ __align__(16) unsigned short Bs[128 * 64];
  const int t    = threadIdx.x;
  const int lane = t & 63;
  const int wave = t >> 6;
  const long brow = (long)blockIdx.x * 128;
  const int  bcol = blockIdx.y * 128;
  const int  wr   = (wave >> 1) * 64;
  const int  wc   = (wave & 1) * 64;

  f32x4 acc[4][4] = {};

  const long aoff = (brow + (t >> 3)) * (long)lda + ((t & 7) * 8);
  const long boff = ((long)(bcol + (t >> 3))) * K + ((t & 7) * 8);
  unsigned short* al0 = As + t * 8;
  unsigned short* bl0 = Bs + t * 8;

  for (int k0 = 0; k0 < K; k0 += 64) {
    const unsigned short* ag = ((k0 < KA0) ? (A0 + k0) : (A1 + (k0 - KA0))) + aoff;
    const unsigned short* bg = BT + boff + k0;
#pragma unroll
    for (int r = 0; r < 4; ++r) {
      gl_lds16(ag + (long)r * 32 * lda, al0 + r * 2048);
      gl_lds16(bg + (long)r * 32 * K, bl0 + r * 2048);
    }
    __syncthreads();
    const unsigned short* ab = As + (wr + (lane & 15)) * 64 + ((lane >> 4) * 8);
    const unsigned short* bb = Bs + (wc + (lane & 15)) * 64 + ((lane >> 4) * 8);
#pragma unroll
    for (int kk = 0; kk < 64; kk += 32) {
      bf16x8 af[4], bfr[4];
#pragma unroll
      for (int m = 0; m < 4; ++m) af[m] = *(const bf16x8*)(ab + m * 16 * 64 + kk);
#pragma unroll
      for (int n = 0; n < 4; ++n) bfr[n] = *(const bf16x8*)(bb + n * 16 * 64 + kk);
#pragma unroll
      for (int m = 0; m < 4; ++m)
#pragma unroll
        for (int n = 0; n < 4; ++n)
          acc[m][n] = __builtin_amdgcn_mfma_f32_16x16x32_bf16(af[m], bfr[n], acc[m][n], 0, 0, 0);
    }
    __syncthreads();
  }

#pragma unroll
  for (int m = 0; m < 4; ++m) {
    int row0 = (int)brow + wr + m * 16 + (lane >> 4) * 4;
#pragma unroll
    for (int n = 0; n < 4; ++n) {
      int col = bcol + wc + n * 16 + (lane & 15);
      if (FINAL) {
        if (col < Nv) {
          float bs = bias[col];
#pragma unroll
          for (int j = 0; j < 4; ++j) {
            int row = row0 + j;
            if (row < Mv) ((float*)outp)[(long)row * ldo + col] = acc[m][n][j] + bs;
          }
        }
      } else {
        float bs = bias[col];
        unsigned short* o = (unsigned short*)outp;
#pragma unroll
        for (int j = 0; j < 4; ++j) o[(long)(row0 + j) * ldo + col] = f2bf(acc[m][n][j] + bs);
      }
    }
  }
}

// ---------------- host launcher ----------------
extern "C" void kernel_launch(void* const* d_in, const int* in_sizes, int n_in, void* d_out,
                              int out_size, void* d_ws, size_t ws_size, hipStream_t stream) {
  char* p = (char*)d_ws;
  auto take = [&](size_t b) {
    char* r = p;
    p += (b + 255) & ~(size_t)255;
    return r;
  };
  int* deg      = (int*)take((size_t)N_NODES * 4);
  int* row_ptr  = (int*)take((size_t)(N_NODES + 4) * 4);
  int* cursor   = (int*)take((size_t)N_NODES * 4);
  int* esrc     = (int*)take((size_t)N_EDGES * 4);
  unsigned short* W1T  = (unsigned short*)take((size_t)512 * 128 * 2);
  unsigned short* W2T  = (unsigned short*)take((size_t)512 * 1024 * 2);
  unsigned short* W3T  = (unsigned short*)take((size_t)512 * 1024 * 2);
  unsigned short* W4lT = (unsigned short*)take((size_t)128 * 512 * 2);
  unsigned short* W4rT = (unsigned short*)take((size_t)128 * 512 * 2);
  float* ssum   = (float*)take(512 * 4);
  float* ssq    = (float*)take(512 * 4);
  float* scale  = (float*)take(512 * 4);
  float* shiftv = (float*)take(512 * 4);
  float* zbias  = (float*)take(512 * 4);
  unsigned short* abuf = (unsigned short*)take((size_t)M_PAD * 512 * 2);  // agg / cat1
  unsigned short* ybuf = (unsigned short*)take((size_t)M_PAD * 512 * 2);  // pre-BN GEMM out / t4
  unsigned short* hbuf = (unsigned short*)take((size_t)M_PAD * 512 * 2);  // activations

  size_t need = (size_t)(p - (char*)d_ws);
  if (need > ws_size || n_in < 20) {
    hipMemsetAsync(d_out, 0, (size_t)out_size * 4, stream);
    return;
  }

  const float* x   = (const float*)d_in[0];
  const int*   ei  = (const int*)d_in[1];
  const int*   srcv = ei;
  const int*   dstv = ei + N_EDGES;
  const float* Wl1 = (const float*)d_in[2];
  const float* bl1 = (const float*)d_in[3];
  const float* Wr1 = (const float*)d_in[4];
  const float* Wl2 = (const float*)d_in[5];
  const float* bl2 = (const float*)d_in[6];
  const float* Wr2 = (const float*)d_in[7];
  const float* Wl3 = (const float*)d_in[8];
  const float* bl3 = (const float*)d_in[9];
  const float* Wr3 = (const float*)d_in[10];
  const float* Wl4 = (const float*)d_in[11];
  const float* bl4 = (const float*)d_in[12];
  const float* Wr4 = (const float*)d_in[13];
  const float* g1  = (const float*)d_in[14];
  const float* b1  = (const float*)d_in[15];
  const float* g2  = (const float*)d_in[16];
  const float* b2  = (const float*)d_in[17];
  const float* g3  = (const float*)d_in[18];
  const float* b3  = (const float*)d_in[19];

  // CSR
  hipMemsetAsync(deg, 0, (size_t)N_NODES * 4, stream);
  hipMemsetAsync(zbias, 0, 512 * 4, stream);
  count_deg<<<(N_EDGES + 255) / 256, 256, 0, stream>>>(dstv, deg);
  scan_kernel<<<1, 1024, 0, stream>>>(deg, row_ptr, cursor);
  scatter_edges<<<(N_EDGES + 255) / 256, 256, 0, stream>>>(srcv, dstv, cursor, esrc);

  // weights
  pack_wt<<<(512 * 128 + 255) / 256, 256, 0, stream>>>(Wl1, Wr1, W1T, 50, 512, 512, 128);
  pack_wt<<<(512 * 1024 + 255) / 256, 256, 0, stream>>>(Wl2, Wr2, W2T, 512, 512, 512, 1024);
  pack_wt<<<(512 * 1024 + 255) / 256, 256, 0, stream>>>(Wl3, Wr3, W3T, 512, 512, 512, 1024);
  pack_w1<<<(128 * 512 + 255) / 256, 256, 0, stream>>>(Wl4, W4lT, 512, 121, 128, 512);
  pack_w1<<<(128 * 512 + 255) / 256, 256, 0, stream>>>(Wr4, W4rT, 512, 121, 128, 512);

  dim3 gemm_grid(391, 4);
  int bn_blocks = (int)(((long)M_PAD * 512 / 8) / 256);

  // ---- layer 1 ----
  prep1v<<<M_PAD, 256, 0, stream>>>(x, row_ptr, esrc, abuf);
  gemm_bf16<0><<<gemm_grid, 256, 0, stream>>>(abuf, abuf, 128, 128, W1T, 128, bl1, ybuf, 512,
                                              M_PAD, 512);
  hipMemsetAsync(ssum, 0, 512 * 4, stream);
  hipMemsetAsync(ssq, 0, 512 * 4, stream);
  bn_stats<<<dim3(4, 196), 256, 0, stream>>>(ybuf, ssum, ssq);
  bn_finalize<<<1, 512, 0, stream>>>(ssum, ssq, g1, b1, scale, shiftv);
  bn_relu<<<bn_blocks, 256, 0, stream>>>(ybuf, scale, shiftv, hbuf);

  // ---- layer 2 ----
  agg_mean512<<<M_PAD, 256, 0, stream>>>(row_ptr, esrc, hbuf, abuf);
  gemm_bf16<0><<<gemm_grid, 256, 0, stream>>>(abuf, hbuf, 512, 512, W2T, 1024, bl2, ybuf, 512,
                                              M_PAD, 512);
  hipMemsetAsync(ssum, 0, 512 * 4, stream);
  hipMemsetAsync(ssq, 0, 512 * 4, stream);
  bn_stats<<<dim3(4, 196), 256, 0, stream>>>(ybuf, ssum, ssq);
  bn_finalize<<<1, 512, 0, stream>>>(ssum, ssq, g2, b2, scale, shiftv);
  bn_relu<<<bn_blocks, 256, 0, stream>>>(ybuf, scale, shiftv, hbuf);

  // ---- layer 3 ----
  agg_mean512<<<M_PAD, 256, 0, stream>>>(row_ptr, esrc, hbuf, abuf);
  gemm_bf16<0><<<gemm_grid, 256, 0, stream>>>(abuf, hbuf, 512, 512, W3T, 1024, bl3, ybuf, 512,
                                              M_PAD, 512);
  hipMemsetAsync(ssum, 0, 512 * 4, stream);
  hipMemsetAsync(ssq, 0, 512 * 4, stream);
  bn_stats<<<dim3(4, 196), 256, 0, stream>>>(ybuf, ssum, ssq);
  bn_finalize<<<1, 512, 0, stream>>>(ssum, ssq, g3, b3, scale, shiftv);
  bn_relu<<<bn_blocks, 256, 0, stream>>>(ybuf, scale, shiftv, hbuf);

  // ---- layer 4: out = agg(h3@Wl4) + h3@Wr4 + bl4 (agg after transform: 4x less gather) ----
  // t4 = h3 @ Wl4 (no bias!), bf16 [M_PAD][128]
  gemm_bf16<0><<<dim3(391, 1), 256, 0, stream>>>(hbuf, hbuf, 512, 512, W4lT, 512, zbias, ybuf,
                                                 128, M_PAD, 128);
  // d_out = h3 @ Wr4 + bl4, fp32 [50000][121]
  gemm_bf16<1><<<dim3(391, 1), 256, 0, stream>>>(hbuf, hbuf, 512, 512, W4rT, 512, bl4, d_out,
                                                 121, N_NODES, 121);
  // d_out += gather-mean(t4)
  agg_add121<<<(N_NODES + 3) / 4, 256, 0, stream>>>(row_ptr, esrc, ybuf, (float*)d_out);
}

// Round 5
// 740.413 us; speedup vs baseline: 1.6709x; 1.2610x over previous
//
#include <hip/hip_runtime.h>

#define N_NODES 50000
#define N_EDGES 400000
#define M_PAD   50048   // 391 * 128
#define SCAN_B  196     // ceil(N_NODES/256)
#define EPS_BN  1e-5f

typedef short bf16x8 __attribute__((ext_vector_type(8)));
typedef float f32x4 __attribute__((ext_vector_type(4)));

__device__ __forceinline__ float bf2f(unsigned short h) {
  union { unsigned int u; float f; } v; v.u = ((unsigned int)h) << 16; return v.f;
}
__device__ __forceinline__ unsigned short f2bf(float x) {
  union { float f; unsigned int u; } v; v.f = x;
  unsigned int r = v.u + 0x7FFFu + ((v.u >> 16) & 1u);
  return (unsigned short)(r >> 16);
}

// ---------------- CSR build ----------------
__global__ void count_deg(const int* __restrict__ dst, int* __restrict__ deg) {
  int e = blockIdx.x * 256 + threadIdx.x;
  if (e < N_EDGES) {
    int d = dst[e];
    if (d >= 0 && d < N_NODES) atomicAdd(&deg[d], 1);
  }
}

// hierarchical prefix sum over deg[] (parallel; replaces 127us single-block scan)
__global__ void block_sums(const int* __restrict__ deg, int* __restrict__ bsum) {
  __shared__ int sd[256];
  int b = blockIdx.x, t = threadIdx.x;
  int i = b * 256 + t;
  sd[t] = (i < N_NODES) ? deg[i] : 0;
  __syncthreads();
  for (int off = 128; off > 0; off >>= 1) {
    if (t < off) sd[t] += sd[t + off];
    __syncthreads();
  }
  if (t == 0) bsum[b] = sd[0];
}

__global__ void scan_bsums(const int* __restrict__ bsum, int* __restrict__ boff) {
  __shared__ int sd[256];
  int t = threadIdx.x;
  int v = (t < SCAN_B) ? bsum[t] : 0;
  sd[t] = v;
  __syncthreads();
  for (int off = 1; off < 256; off <<= 1) {
    int add = (t >= off) ? sd[t - off] : 0;
    __syncthreads();
    sd[t] += add;
    __syncthreads();
  }
  if (t < SCAN_B) boff[t] = sd[t] - v;  // exclusive
}

__global__ void write_rowptr(const int* __restrict__ deg, const int* __restrict__ boff,
                             int* __restrict__ row_ptr, int* __restrict__ cursor) {
  __shared__ int sd[256];
  int b = blockIdx.x, t = threadIdx.x;
  int i = b * 256 + t;
  int v = (i < N_NODES) ? deg[i] : 0;
  sd[t] = v;
  __syncthreads();
  for (int off = 1; off < 256; off <<= 1) {
    int add = (t >= off) ? sd[t - off] : 0;
    __syncthreads();
    sd[t] += add;
    __syncthreads();
  }
  if (i < N_NODES) {
    int ex = boff[b] + sd[t] - v;
    row_ptr[i] = ex;
    cursor[i]  = ex;
    if (i == N_NODES - 1) row_ptr[N_NODES] = boff[b] + sd[t];
  }
}

__global__ void scatter_edges(const int* __restrict__ src, const int* __restrict__ dst,
                              int* __restrict__ cursor, int* __restrict__ esrc) {
  int e = blockIdx.x * 256 + threadIdx.x;
  if (e < N_EDGES) {
    int d = dst[e];
    int s = src[e];
    if (d >= 0 && d < N_NODES && s >= 0 && s < N_NODES) {
      int p = atomicAdd(&cursor[d], 1);
      esrc[p] = s;
    }
  }
}

// ---------------- weight packs ----------------
__global__ void pack_wt(const float* __restrict__ Wl, const float* __restrict__ Wr,
                        unsigned short* __restrict__ WT, int Keach, int N, int Npad, int Kpad) {
  int idx = blockIdx.x * 256 + threadIdx.x;
  if (idx >= Npad * Kpad) return;
  int n = idx / Kpad, k = idx % Kpad;
  float v = 0.f;
  if (n < N) {
    if (k < Keach) v = Wl[k * N + n];
    else if (k < 2 * Keach) v = Wr[(k - Keach) * N + n];
  }
  WT[idx] = f2bf(v);
}

__global__ void pack_w1(const float* __restrict__ W, unsigned short* __restrict__ WT, int K,
                        int N, int Npad, int Kpad) {
  int idx = blockIdx.x * 256 + threadIdx.x;
  if (idx >= Npad * Kpad) return;
  int n = idx / Kpad, k = idx % Kpad;
  float v = (n < N && k < K) ? W[k * N + n] : 0.f;
  WT[idx] = f2bf(v);
}

// ---------------- layer-1 input build ----------------
__global__ void prep1v(const float* __restrict__ x, const int* __restrict__ row_ptr,
                       const int* __restrict__ esrc, unsigned short* __restrict__ cat1) {
  __shared__ float part[4][64];
  int n = blockIdx.x, t = threadIdx.x;
  int w = t >> 6, lane = t & 63;
  unsigned short* row = cat1 + (long)n * 128;
  if (n >= N_NODES) {
    if (t < 64) { row[t] = 0; row[64 + t] = 0; }
    return;
  }
  int e0 = row_ptr[n], e1 = row_ptr[n + 1];
  float acc = 0.f;
  if (lane < 50) {
    for (int e = e0 + w; e < e1; e += 4) acc += x[(long)esrc[e] * 50 + lane];
  }
  part[w][lane] = acc;
  __syncthreads();
  if (t < 128) {
    if (t < 64) {
      float s = part[0][t] + part[1][t] + part[2][t] + part[3][t];
      float rdeg = (e1 > e0) ? 1.f / (float)(e1 - e0) : 0.f;
      if (t < 50) {
        row[t]      = f2bf(s * rdeg);
        row[50 + t] = f2bf(x[(long)n * 50 + t]);
      }
    } else if (t >= 100) {
      row[t] = 0;
    }
  }
}

// ---------------- mean aggregation, 512 cols ----------------
__global__ void agg_mean512(const int* __restrict__ row_ptr, const int* __restrict__ esrc,
                            const unsigned short* __restrict__ h,
                            unsigned short* __restrict__ agg) {
  __shared__ float part[4][512];
  int n = blockIdx.x, t = threadIdx.x;
  int w = t >> 6, lane = t & 63;
  unsigned int* outw = (unsigned int*)(agg + (long)n * 512);
  if (n >= N_NODES) { outw[t] = 0; return; }
  int e0 = row_ptr[n], e1 = row_ptr[n + 1];
  float acc[8] = {0.f, 0.f, 0.f, 0.f, 0.f, 0.f, 0.f, 0.f};
  for (int e = e0 + w; e < e1; e += 4) {
    int s = esrc[e];
    uint4 v = *(const uint4*)(h + (long)s * 512 + lane * 8);
    const unsigned short* pv = (const unsigned short*)&v;
#pragma unroll
    for (int j = 0; j < 8; ++j) acc[j] += bf2f(pv[j]);
  }
  float* pw = &part[w][lane * 8];
#pragma unroll
  for (int j = 0; j < 8; ++j) pw[j] = acc[j];
  __syncthreads();
  int c = t * 2;
  float s0 = part[0][c] + part[1][c] + part[2][c] + part[3][c];
  float s1 = part[0][c + 1] + part[1][c + 1] + part[2][c + 1] + part[3][c + 1];
  float rdeg = (e1 > e0) ? 1.f / (float)(e1 - e0) : 0.f;
  unsigned int pk = (unsigned int)f2bf(s0 * rdeg) | ((unsigned int)f2bf(s1 * rdeg) << 16);
  outw[t] = pk;
}

// ---------------- layer-4 gather-add, 121 cols ----------------
__global__ void agg_add121(const int* __restrict__ row_ptr, const int* __restrict__ esrc,
                           const unsigned short* __restrict__ t4, float* __restrict__ out) {
  int n = blockIdx.x * 4 + (threadIdx.x >> 6);
  if (n >= N_NODES) return;
  int lane = threadIdx.x & 63;
  int g = lane >> 4;
  int cl = lane & 15;
  int e0 = row_ptr[n], e1 = row_ptr[n + 1];
  float acc[8] = {0.f, 0.f, 0.f, 0.f, 0.f, 0.f, 0.f, 0.f};
  for (int e = e0 + g; e < e1; e += 4) {
    int s = esrc[e];
    uint4 v = *(const uint4*)(t4 + (long)s * 128 + cl * 8);
    const unsigned short* pv = (const unsigned short*)&v;
#pragma unroll
    for (int j = 0; j < 8; ++j) acc[j] += bf2f(pv[j]);
  }
#pragma unroll
  for (int j = 0; j < 8; ++j) {
    acc[j] += __shfl_xor(acc[j], 16);
    acc[j] += __shfl_xor(acc[j], 32);
  }
  if (g == 0) {
    float rdeg = (e1 > e0) ? 1.f / (float)(e1 - e0) : 0.f;
#pragma unroll
    for (int j = 0; j < 8; ++j) {
      int c = cl * 8 + j;
      if (c < 121) out[(long)n * 121 + c] += acc[j] * rdeg;
    }
  }
}

// ---------------- BN finalize / apply+ReLU ----------------
__global__ void bn_finalize(const float* __restrict__ ssum, const float* __restrict__ ssq,
                            const float* __restrict__ g, const float* __restrict__ b,
                            float* __restrict__ scale, float* __restrict__ shiftv) {
  int c = threadIdx.x;
  float mu  = ssum[c] * (1.f / N_NODES);
  float var = ssq[c] * (1.f / N_NODES) - mu * mu;
  float rs  = rsqrtf(var + EPS_BN);
  float sc  = g[c] * rs;
  scale[c]  = sc;
  shiftv[c] = b[c] - mu * sc;
}

__global__ void bn_relu(const unsigned short* __restrict__ y, const float* __restrict__ scale,
                        const float* __restrict__ shiftv, unsigned short* __restrict__ hout) {
  long idx = ((long)blockIdx.x * 256 + threadIdx.x) * 8;
  if (idx >= (long)M_PAD * 512) return;
  int row = (int)(idx >> 9);
  int col = (int)(idx & 511);
  unsigned short* o = hout + idx;
  if (row >= N_NODES) {
    uint4 z; z.x = 0; z.y = 0; z.z = 0; z.w = 0;
    *(uint4*)o = z;
    return;
  }
  uint4 v = *(const uint4*)(y + idx);
  unsigned short* p = (unsigned short*)&v;
  uint4 rr;
  unsigned short* q = (unsigned short*)&rr;
#pragma unroll
  for (int j = 0; j < 8; ++j) {
    float f = bf2f(p[j]) * scale[col + j] + shiftv[col + j];
    q[j] = f2bf(fmaxf(f, 0.f));
  }
  *(uint4*)o = rr;
}

// ---------------- bf16 MFMA GEMM with optional fused BN-stats epilogue ----------------
__device__ __forceinline__ void gl_lds16(const void* g, void* l) {
  __builtin_amdgcn_global_load_lds((const __attribute__((address_space(1))) unsigned int*)g,
                                   (__attribute__((address_space(3))) unsigned int*)l, 16, 0, 0);
}

template <int FINAL, int STATS>
__global__ void gemm_bf16(const unsigned short* __restrict__ A0,
                          const unsigned short* __restrict__ A1, int lda, int KA0,
                          const unsigned short* __restrict__ BT, int K,
                          const float* __restrict__ bias, void* __restrict__ outp, int ldo,
                          int Mv, int Nv, float* __restrict__ ssum, float* __restrict__ ssq) {
  __shared__ __align__(16) unsigned short As[128 * 64];
  __shared__ __align__(16) unsigned short Bs[128 * 64];
  const int t    = threadIdx.x;
  const int lane = t & 63;
  const int wave = t >> 6;
  const long brow = (long)blockIdx.x * 128;
  const int  bcol = blockIdx.y * 128;
  const int  wr   = (wave >> 1) * 64;
  const int  wc   = (wave & 1) * 64;

  f32x4 acc[4][4] = {};

  const long aoff = (brow + (t >> 3)) * (long)lda + ((t & 7) * 8);
  const long boff = ((long)(bcol + (t >> 3))) * K + ((t & 7) * 8);
  unsigned short* al0 = As + t * 8;
  unsigned short* bl0 = Bs + t * 8;

  for (int k0 = 0; k0 < K; k0 += 64) {
    const unsigned short* ag = ((k0 < KA0) ? (A0 + k0) : (A1 + (k0 - KA0))) + aoff;
    const unsigned short* bg = BT + boff + k0;
#pragma unroll
    for (int r = 0; r < 4; ++r) {
      gl_lds16(ag + (long)r * 32 * lda, al0 + r * 2048);
      gl_lds16(bg + (long)r * 32 * K, bl0 + r * 2048);
    }
    __syncthreads();
    const unsigned short* ab = As + (wr + (lane & 15)) * 64 + ((lane >> 4) * 8);
    const unsigned short* bb = Bs + (wc + (lane & 15)) * 64 + ((lane >> 4) * 8);
#pragma unroll
    for (int kk = 0; kk < 64; kk += 32) {
      bf16x8 af[4], bfr[4];
#pragma unroll
      for (int m = 0; m < 4; ++m) af[m] = *(const bf16x8*)(ab + m * 16 * 64 + kk);
#pragma unroll
      for (int n = 0; n < 4; ++n) bfr[n] = *(const bf16x8*)(bb + n * 16 * 64 + kk);
#pragma unroll
      for (int m = 0; m < 4; ++m)
#pragma unroll
        for (int n = 0; n < 4; ++n)
          acc[m][n] = __builtin_amdgcn_mfma_f32_16x16x32_bf16(af[m], bfr[n], acc[m][n], 0, 0, 0);
    }
    __syncthreads();
  }

  // LDS buffer for stats reduction (reuse As; free after last barrier)
  float* sstat = (float*)As;
  if (STATS) {
    if (t < 128) { sstat[t] = 0.f; sstat[128 + t] = 0.f; }
    __syncthreads();
  }

#pragma unroll
  for (int m = 0; m < 4; ++m) {
    int row0 = (int)brow + wr + m * 16 + (lane >> 4) * 4;
#pragma unroll
    for (int n = 0; n < 4; ++n) {
      int col = bcol + wc + n * 16 + (lane & 15);
      if (FINAL) {
        if (col < Nv) {
          float bs = bias[col];
#pragma unroll
          for (int j = 0; j < 4; ++j) {
            int row = row0 + j;
            if (row < Mv) ((float*)outp)[(long)row * ldo + col] = acc[m][n][j] + bs;
          }
        }
      } else {
        float bs = bias[col];
        unsigned short* o = (unsigned short*)outp;
#pragma unroll
        for (int j = 0; j < 4; ++j) o[(long)(row0 + j) * ldo + col] = f2bf(acc[m][n][j] + bs);
      }
    }
  }

  if (STATS) {
#pragma unroll
    for (int n = 0; n < 4; ++n) {
      int colL = wc + n * 16 + (lane & 15);
      float bs = bias[bcol + colL];
      float s = 0.f, s2 = 0.f;
#pragma unroll
      for (int m = 0; m < 4; ++m) {
        int row0 = (int)brow + wr + m * 16 + (lane >> 4) * 4;
#pragma unroll
        for (int j = 0; j < 4; ++j) {
          if (row0 + j < N_NODES) {
            float v = acc[m][n][j] + bs;
            s += v;
            s2 += v * v;
          }
        }
      }
      atomicAdd(&sstat[colL], s);
      atomicAdd(&sstat[128 + colL], s2);
    }
    __syncthreads();
    if (t < 128) {
      atomicAdd(&ssum[bcol + t], sstat[t]);
      atomicAdd(&ssq[bcol + t], sstat[128 + t]);
    }
  }
}

// ---------------- host launcher ----------------
extern "C" void kernel_launch(void* const* d_in, const int* in_sizes, int n_in, void* d_out,
                              int out_size, void* d_ws, size_t ws_size, hipStream_t stream) {
  char* p = (char*)d_ws;
  auto take = [&](size_t b) {
    char* r = p;
    p += (b + 255) & ~(size_t)255;
    return r;
  };
  int* deg      = (int*)take((size_t)N_NODES * 4);
  int* row_ptr  = (int*)take((size_t)(N_NODES + 4) * 4);
  int* cursor   = (int*)take((size_t)N_NODES * 4);
  int* esrc     = (int*)take((size_t)N_EDGES * 4);
  int* bsum     = (int*)take(256 * 4);
  int* boffb    = (int*)take(256 * 4);
  unsigned short* W1T  = (unsigned short*)take((size_t)512 * 128 * 2);
  unsigned short* W2T  = (unsigned short*)take((size_t)512 * 1024 * 2);
  unsigned short* W3T  = (unsigned short*)take((size_t)512 * 1024 * 2);
  unsigned short* W4lT = (unsigned short*)take((size_t)128 * 512 * 2);
  unsigned short* W4rT = (unsigned short*)take((size_t)128 * 512 * 2);
  float* ssum   = (float*)take(512 * 4);
  float* ssq    = (float*)take(512 * 4);
  float* scale  = (float*)take(512 * 4);
  float* shiftv = (float*)take(512 * 4);
  float* zbias  = (float*)take(512 * 4);
  unsigned short* abuf = (unsigned short*)take((size_t)M_PAD * 512 * 2);
  unsigned short* ybuf = (unsigned short*)take((size_t)M_PAD * 512 * 2);
  unsigned short* hbuf = (unsigned short*)take((size_t)M_PAD * 512 * 2);

  size_t need = (size_t)(p - (char*)d_ws);
  if (need > ws_size || n_in < 20) {
    hipMemsetAsync(d_out, 0, (size_t)out_size * 4, stream);
    return;
  }

  const float* x   = (const float*)d_in[0];
  const int*   ei  = (const int*)d_in[1];
  const int*   srcv = ei;
  const int*   dstv = ei + N_EDGES;
  const float* Wl1 = (const float*)d_in[2];
  const float* bl1 = (const float*)d_in[3];
  const float* Wr1 = (const float*)d_in[4];
  const float* Wl2 = (const float*)d_in[5];
  const float* bl2 = (const float*)d_in[6];
  const float* Wr2 = (const float*)d_in[7];
  const float* Wl3 = (const float*)d_in[8];
  const float* bl3 = (const float*)d_in[9];
  const float* Wr3 = (const float*)d_in[10];
  const float* Wl4 = (const float*)d_in[11];
  const float* bl4 = (const float*)d_in[12];
  const float* Wr4 = (const float*)d_in[13];
  const float* g1  = (const float*)d_in[14];
  const float* b1  = (const float*)d_in[15];
  const float* g2  = (const float*)d_in[16];
  const float* b2  = (const float*)d_in[17];
  const float* g3  = (const float*)d_in[18];
  const float* b3  = (const float*)d_in[19];

  // CSR (parallel scan)
  hipMemsetAsync(deg, 0, (size_t)N_NODES * 4, stream);
  hipMemsetAsync(zbias, 0, 512 * 4, stream);
  count_deg<<<(N_EDGES + 255) / 256, 256, 0, stream>>>(dstv, deg);
  block_sums<<<SCAN_B, 256, 0, stream>>>(deg, bsum);
  scan_bsums<<<1, 256, 0, stream>>>(bsum, boffb);
  write_rowptr<<<SCAN_B, 256, 0, stream>>>(deg, boffb, row_ptr, cursor);
  scatter_edges<<<(N_EDGES + 255) / 256, 256, 0, stream>>>(srcv, dstv, cursor, esrc);

  // weights
  pack_wt<<<(512 * 128 + 255) / 256, 256, 0, stream>>>(Wl1, Wr1, W1T, 50, 512, 512, 128);
  pack_wt<<<(512 * 1024 + 255) / 256, 256, 0, stream>>>(Wl2, Wr2, W2T, 512, 512, 512, 1024);
  pack_wt<<<(512 * 1024 + 255) / 256, 256, 0, stream>>>(Wl3, Wr3, W3T, 512, 512, 512, 1024);
  pack_w1<<<(128 * 512 + 255) / 256, 256, 0, stream>>>(Wl4, W4lT, 512, 121, 128, 512);
  pack_w1<<<(128 * 512 + 255) / 256, 256, 0, stream>>>(Wr4, W4rT, 512, 121, 128, 512);

  dim3 gemm_grid(391, 4);
  int bn_blocks = (int)(((long)M_PAD * 512 / 8) / 256);

  // ---- layer 1 ----
  prep1v<<<M_PAD, 256, 0, stream>>>(x, row_ptr, esrc, abuf);
  hipMemsetAsync(ssum, 0, 512 * 4, stream);
  hipMemsetAsync(ssq, 0, 512 * 4, stream);
  gemm_bf16<0, 1><<<gemm_grid, 256, 0, stream>>>(abuf, abuf, 128, 128, W1T, 128, bl1, ybuf, 512,
                                                 M_PAD, 512, ssum, ssq);
  bn_finalize<<<1, 512, 0, stream>>>(ssum, ssq, g1, b1, scale, shiftv);
  bn_relu<<<bn_blocks, 256, 0, stream>>>(ybuf, scale, shiftv, hbuf);

  // ---- layer 2 ----
  agg_mean512<<<M_PAD, 256, 0, stream>>>(row_ptr, esrc, hbuf, abuf);
  hipMemsetAsync(ssum, 0, 512 * 4, stream);
  hipMemsetAsync(ssq, 0, 512 * 4, stream);
  gemm_bf16<0, 1><<<gemm_grid, 256, 0, stream>>>(abuf, hbuf, 512, 512, W2T, 1024, bl2, ybuf, 512,
                                                 M_PAD, 512, ssum, ssq);
  bn_finalize<<<1, 512, 0, stream>>>(ssum, ssq, g2, b2, scale, shiftv);
  bn_relu<<<bn_blocks, 256, 0, stream>>>(ybuf, scale, shiftv, hbuf);

  // ---- layer 3 ----
  agg_mean512<<<M_PAD, 256, 0, stream>>>(row_ptr, esrc, hbuf, abuf);
  hipMemsetAsync(ssum, 0, 512 * 4, stream);
  hipMemsetAsync(ssq, 0, 512 * 4, stream);
  gemm_bf16<0, 1><<<gemm_grid, 256, 0, stream>>>(abuf, hbuf, 512, 512, W3T, 1024, bl3, ybuf, 512,
                                                 M_PAD, 512, ssum, ssq);
  bn_finalize<<<1, 512, 0, stream>>>(ssum, ssq, g3, b3, scale, shiftv);
  bn_relu<<<bn_blocks, 256, 0, stream>>>(ybuf, scale, shiftv, hbuf);

  // ---- layer 4: out = agg(h3@Wl4) + h3@Wr4 + bl4 ----
  gemm_bf16<0, 0><<<dim3(391, 1), 256, 0, stream>>>(hbuf, hbuf, 512, 512, W4lT, 512, zbias, ybuf,
                                                    128, M_PAD, 128, nullptr, nullptr);
  gemm_bf16<1, 0><<<dim3(391, 1), 256, 0, stream>>>(hbuf, hbuf, 512, 512, W4rT, 512, bl4, d_out,
                                                    121, N_NODES, 121, nullptr, nullptr);
  agg_add121<<<(N_NODES + 3) / 4, 256, 0, stream>>>(row_ptr, esrc, ybuf, (float*)d_out);
}

// Round 6
// 714.356 us; speedup vs baseline: 1.7318x; 1.0365x over previous
//
#include <hip/hip_runtime.h>

#define N_NODES 50000
#define N_EDGES 400000
#define M_PAD   50048   // 391 * 128
#define SCAN_B  196     // ceil(N_NODES/256)
#define EPS_BN  1e-5f

typedef short bf16x8 __attribute__((ext_vector_type(8)));
typedef float f32x4 __attribute__((ext_vector_type(4)));

__device__ __forceinline__ float bf2f(unsigned short h) {
  union { unsigned int u; float f; } v; v.u = ((unsigned int)h) << 16; return v.f;
}
__device__ __forceinline__ unsigned short f2bf(float x) {
  union { float f; unsigned int u; } v; v.f = x;
  unsigned int r = v.u + 0x7FFFu + ((v.u >> 16) & 1u);
  return (unsigned short)(r >> 16);
}

// ---------------- CSR build ----------------
__global__ void count_deg(const int* __restrict__ dst, int* __restrict__ deg) {
  int e = blockIdx.x * 256 + threadIdx.x;
  if (e < N_EDGES) {
    int d = dst[e];
    if (d >= 0 && d < N_NODES) atomicAdd(&deg[d], 1);
  }
}

__global__ void block_sums(const int* __restrict__ deg, int* __restrict__ bsum) {
  __shared__ int sd[256];
  int b = blockIdx.x, t = threadIdx.x;
  int i = b * 256 + t;
  sd[t] = (i < N_NODES) ? deg[i] : 0;
  __syncthreads();
  for (int off = 128; off > 0; off >>= 1) {
    if (t < off) sd[t] += sd[t + off];
    __syncthreads();
  }
  if (t == 0) bsum[b] = sd[0];
}

__global__ void scan_bsums(const int* __restrict__ bsum, int* __restrict__ boff) {
  __shared__ int sd[256];
  int t = threadIdx.x;
  int v = (t < SCAN_B) ? bsum[t] : 0;
  sd[t] = v;
  __syncthreads();
  for (int off = 1; off < 256; off <<= 1) {
    int add = (t >= off) ? sd[t - off] : 0;
    __syncthreads();
    sd[t] += add;
    __syncthreads();
  }
  if (t < SCAN_B) boff[t] = sd[t] - v;  // exclusive
}

__global__ void write_rowptr(const int* __restrict__ deg, const int* __restrict__ boff,
                             int* __restrict__ row_ptr, int* __restrict__ cursor) {
  __shared__ int sd[256];
  int b = blockIdx.x, t = threadIdx.x;
  int i = b * 256 + t;
  int v = (i < N_NODES) ? deg[i] : 0;
  sd[t] = v;
  __syncthreads();
  for (int off = 1; off < 256; off <<= 1) {
    int add = (t >= off) ? sd[t - off] : 0;
    __syncthreads();
    sd[t] += add;
    __syncthreads();
  }
  if (i < N_NODES) {
    int ex = boff[b] + sd[t] - v;
    row_ptr[i] = ex;
    cursor[i]  = ex;
    if (i == N_NODES - 1) row_ptr[N_NODES] = boff[b] + sd[t];
  }
}

__global__ void scatter_edges(const int* __restrict__ src, const int* __restrict__ dst,
                              int* __restrict__ cursor, int* __restrict__ esrc) {
  int e = blockIdx.x * 256 + threadIdx.x;
  if (e < N_EDGES) {
    int d = dst[e];
    int s = src[e];
    if (d >= 0 && d < N_NODES && s >= 0 && s < N_NODES) {
      int p = atomicAdd(&cursor[d], 1);
      esrc[p] = s;
    }
  }
}

// ---------------- weight packs ----------------
__global__ void pack_wt(const float* __restrict__ Wl, const float* __restrict__ Wr,
                        unsigned short* __restrict__ WT, int Keach, int N, int Npad, int Kpad) {
  int idx = blockIdx.x * 256 + threadIdx.x;
  if (idx >= Npad * Kpad) return;
  int n = idx / Kpad, k = idx % Kpad;
  float v = 0.f;
  if (n < N) {
    if (k < Keach) v = Wl[k * N + n];
    else if (k < 2 * Keach) v = Wr[(k - Keach) * N + n];
  }
  WT[idx] = f2bf(v);
}

__global__ void pack_w1(const float* __restrict__ W, unsigned short* __restrict__ WT, int K,
                        int N, int Npad, int Kpad) {
  int idx = blockIdx.x * 256 + threadIdx.x;
  if (idx >= Npad * Kpad) return;
  int n = idx / Kpad, k = idx % Kpad;
  float v = (n < N && k < K) ? W[k * N + n] : 0.f;
  WT[idx] = f2bf(v);
}

// ---------------- layer-1 input build ----------------
__global__ void prep1v(const float* __restrict__ x, const int* __restrict__ row_ptr,
                       const int* __restrict__ esrc, unsigned short* __restrict__ cat1) {
  __shared__ float part[4][64];
  int n = blockIdx.x, t = threadIdx.x;
  int w = t >> 6, lane = t & 63;
  unsigned short* row = cat1 + (long)n * 128;
  if (n >= N_NODES) {
    if (t < 64) { row[t] = 0; row[64 + t] = 0; }
    return;
  }
  int e0 = row_ptr[n], e1 = row_ptr[n + 1];
  float acc = 0.f;
  if (lane < 50) {
    for (int e = e0 + w; e < e1; e += 4) acc += x[(long)esrc[e] * 50 + lane];
  }
  part[w][lane] = acc;
  __syncthreads();
  if (t < 128) {
    if (t < 64) {
      float s = part[0][t] + part[1][t] + part[2][t] + part[3][t];
      float rdeg = (e1 > e0) ? 1.f / (float)(e1 - e0) : 0.f;
      if (t < 50) {
        row[t]      = f2bf(s * rdeg);
        row[50 + t] = f2bf(x[(long)n * 50 + t]);
      }
    } else if (t >= 100) {
      row[t] = 0;
    }
  }
}

// ---------------- mean aggregation, 512 cols ----------------
__global__ void agg_mean512(const int* __restrict__ row_ptr, const int* __restrict__ esrc,
                            const unsigned short* __restrict__ h,
                            unsigned short* __restrict__ agg) {
  __shared__ float part[4][512];
  int n = blockIdx.x, t = threadIdx.x;
  int w = t >> 6, lane = t & 63;
  unsigned int* outw = (unsigned int*)(agg + (long)n * 512);
  if (n >= N_NODES) { outw[t] = 0; return; }
  int e0 = row_ptr[n], e1 = row_ptr[n + 1];
  float acc[8] = {0.f, 0.f, 0.f, 0.f, 0.f, 0.f, 0.f, 0.f};
  for (int e = e0 + w; e < e1; e += 4) {
    int s = esrc[e];
    uint4 v = *(const uint4*)(h + (long)s * 512 + lane * 8);
    const unsigned short* pv = (const unsigned short*)&v;
#pragma unroll
    for (int j = 0; j < 8; ++j) acc[j] += bf2f(pv[j]);
  }
  float* pw = &part[w][lane * 8];
#pragma unroll
  for (int j = 0; j < 8; ++j) pw[j] = acc[j];
  __syncthreads();
  int c = t * 2;
  float s0 = part[0][c] + part[1][c] + part[2][c] + part[3][c];
  float s1 = part[0][c + 1] + part[1][c + 1] + part[2][c + 1] + part[3][c + 1];
  float rdeg = (e1 > e0) ? 1.f / (float)(e1 - e0) : 0.f;
  unsigned int pk = (unsigned int)f2bf(s0 * rdeg) | ((unsigned int)f2bf(s1 * rdeg) << 16);
  outw[t] = pk;
}

// ---------------- layer-4 gather-add, 121 cols ----------------
__global__ void agg_add121(const int* __restrict__ row_ptr, const int* __restrict__ esrc,
                           const unsigned short* __restrict__ t4, float* __restrict__ out) {
  int n = blockIdx.x * 4 + (threadIdx.x >> 6);
  if (n >= N_NODES) return;
  int lane = threadIdx.x & 63;
  int g = lane >> 4;
  int cl = lane & 15;
  int e0 = row_ptr[n], e1 = row_ptr[n + 1];
  float acc[8] = {0.f, 0.f, 0.f, 0.f, 0.f, 0.f, 0.f, 0.f};
  for (int e = e0 + g; e < e1; e += 4) {
    int s = esrc[e];
    uint4 v = *(const uint4*)(t4 + (long)s * 128 + cl * 8);
    const unsigned short* pv = (const unsigned short*)&v;
#pragma unroll
    for (int j = 0; j < 8; ++j) acc[j] += bf2f(pv[j]);
  }
#pragma unroll
  for (int j = 0; j < 8; ++j) {
    acc[j] += __shfl_xor(acc[j], 16);
    acc[j] += __shfl_xor(acc[j], 32);
  }
  if (g == 0) {
    float rdeg = (e1 > e0) ? 1.f / (float)(e1 - e0) : 0.f;
#pragma unroll
    for (int j = 0; j < 8; ++j) {
      int c = cl * 8 + j;
      if (c < 121) out[(long)n * 121 + c] += acc[j] * rdeg;
    }
  }
}

// ---------------- BN finalize / apply+ReLU ----------------
__global__ void bn_finalize(const float* __restrict__ ssum, const float* __restrict__ ssq,
                            const float* __restrict__ g, const float* __restrict__ b,
                            float* __restrict__ scale, float* __restrict__ shiftv) {
  int c = threadIdx.x;
  float mu  = ssum[c] * (1.f / N_NODES);
  float var = ssq[c] * (1.f / N_NODES) - mu * mu;
  float rs  = rsqrtf(var + EPS_BN);
  float sc  = g[c] * rs;
  scale[c]  = sc;
  shiftv[c] = b[c] - mu * sc;
}

__global__ void bn_relu(const unsigned short* __restrict__ y, const float* __restrict__ scale,
                        const float* __restrict__ shiftv, unsigned short* __restrict__ hout) {
  long idx = ((long)blockIdx.x * 256 + threadIdx.x) * 8;
  if (idx >= (long)M_PAD * 512) return;
  int row = (int)(idx >> 9);
  int col = (int)(idx & 511);
  unsigned short* o = hout + idx;
  if (row >= N_NODES) {
    uint4 z; z.x = 0; z.y = 0; z.z = 0; z.w = 0;
    *(uint4*)o = z;
    return;
  }
  uint4 v = *(const uint4*)(y + idx);
  unsigned short* p = (unsigned short*)&v;
  uint4 rr;
  unsigned short* q = (unsigned short*)&rr;
#pragma unroll
  for (int j = 0; j < 8; ++j) {
    float f = bf2f(p[j]) * scale[col + j] + shiftv[col + j];
    q[j] = f2bf(fmaxf(f, 0.f));
  }
  *(uint4*)o = rr;
}

// ---------------- bf16 MFMA GEMM ----------------
// blockIdx.x = N-block (fastest-varying -> adjacent blocks share the A panel, L2 reuse)
// blockIdx.y = M-block
// MODE 0: bf16 out (+bias) with fused BN-stats epilogue (layers 1-3)
// MODE 1: layer-4 split epilogue: cols 0..127 -> bf16 t4 (no bias), cols 128..248 -> f32 d_out+bias
__device__ __forceinline__ void gl_lds16(const void* g, void* l) {
  __builtin_amdgcn_global_load_lds((const __attribute__((address_space(1))) unsigned int*)g,
                                   (__attribute__((address_space(3))) unsigned int*)l, 16, 0, 0);
}

template <int MODE>
__global__ void gemm_bf16(const unsigned short* __restrict__ A0,
                          const unsigned short* __restrict__ A1, int lda, int KA0,
                          const unsigned short* __restrict__ BT, int K,
                          const float* __restrict__ bias, unsigned short* __restrict__ outb,
                          int ldob, float* __restrict__ outf, float* __restrict__ ssum,
                          float* __restrict__ ssq) {
  __shared__ __align__(16) unsigned short As[128 * 64];
  __shared__ __align__(16) unsigned short Bs[128 * 64];
  const int t    = threadIdx.x;
  const int lane = t & 63;
  const int wave = t >> 6;
  const long brow = (long)blockIdx.y * 128;
  const int  bcol = blockIdx.x * 128;
  const int  wr   = (wave >> 1) * 64;
  const int  wc   = (wave & 1) * 64;

  f32x4 acc[4][4] = {};

  const long aoff = (brow + (t >> 3)) * (long)lda + ((t & 7) * 8);
  const long boff = ((long)(bcol + (t >> 3))) * K + ((t & 7) * 8);
  unsigned short* al0 = As + t * 8;
  unsigned short* bl0 = Bs + t * 8;

  for (int k0 = 0; k0 < K; k0 += 64) {
    const unsigned short* ag = ((k0 < KA0) ? (A0 + k0) : (A1 + (k0 - KA0))) + aoff;
    const unsigned short* bg = BT + boff + k0;
#pragma unroll
    for (int r = 0; r < 4; ++r) {
      gl_lds16(ag + (long)r * 32 * lda, al0 + r * 2048);
      gl_lds16(bg + (long)r * 32 * K, bl0 + r * 2048);
    }
    __syncthreads();
    const unsigned short* ab = As + (wr + (lane & 15)) * 64 + ((lane >> 4) * 8);
    const unsigned short* bb = Bs + (wc + (lane & 15)) * 64 + ((lane >> 4) * 8);
#pragma unroll
    for (int kk = 0; kk < 64; kk += 32) {
      bf16x8 af[4], bfr[4];
#pragma unroll
      for (int m = 0; m < 4; ++m) af[m] = *(const bf16x8*)(ab + m * 16 * 64 + kk);
#pragma unroll
      for (int n = 0; n < 4; ++n) bfr[n] = *(const bf16x8*)(bb + n * 16 * 64 + kk);
#pragma unroll
      for (int m = 0; m < 4; ++m)
#pragma unroll
        for (int n = 0; n < 4; ++n)
          acc[m][n] = __builtin_amdgcn_mfma_f32_16x16x32_bf16(af[m], bfr[n], acc[m][n], 0, 0, 0);
    }
    __syncthreads();
  }

  float* sstat = (float*)As;  // reuse As for stats reduction
  if (MODE == 0) {
    if (t < 128) { sstat[t] = 0.f; sstat[128 + t] = 0.f; }
    __syncthreads();
  }

#pragma unroll
  for (int m = 0; m < 4; ++m) {
    int row0 = (int)brow + wr + m * 16 + (lane >> 4) * 4;
#pragma unroll
    for (int n = 0; n < 4; ++n) {
      int col = bcol + wc + n * 16 + (lane & 15);
      if (MODE == 0) {
        float bs = bias[col];
#pragma unroll
        for (int j = 0; j < 4; ++j)
          outb[(long)(row0 + j) * ldob + col] = f2bf(acc[m][n][j] + bs);
      } else {
        if (col < 128) {
          // t4 half: no bias
#pragma unroll
          for (int j = 0; j < 4; ++j)
            outb[(long)(row0 + j) * ldob + col] = f2bf(acc[m][n][j]);
        } else {
          int c2 = col - 128;
          if (c2 < 121) {
            float bs = bias[c2];
#pragma unroll
            for (int j = 0; j < 4; ++j) {
              int row = row0 + j;
              if (row < N_NODES) outf[(long)row * 121 + c2] = acc[m][n][j] + bs;
            }
          }
        }
      }
    }
  }

  if (MODE == 0) {
#pragma unroll
    for (int n = 0; n < 4; ++n) {
      int colL = wc + n * 16 + (lane & 15);
      float bs = bias[bcol + colL];
      float s = 0.f, s2 = 0.f;
#pragma unroll
      for (int m = 0; m < 4; ++m) {
        int row0 = (int)brow + wr + m * 16 + (lane >> 4) * 4;
#pragma unroll
        for (int j = 0; j < 4; ++j) {
          if (row0 + j < N_NODES) {
            float v = acc[m][n][j] + bs;
            s += v;
            s2 += v * v;
          }
        }
      }
      atomicAdd(&sstat[colL], s);
      atomicAdd(&sstat[128 + colL], s2);
    }
    __syncthreads();
    if (t < 128) {
      atomicAdd(&ssum[bcol + t], sstat[t]);
      atomicAdd(&ssq[bcol + t], sstat[128 + t]);
    }
  }
}

// ---------------- host launcher ----------------
extern "C" void kernel_launch(void* const* d_in, const int* in_sizes, int n_in, void* d_out,
                              int out_size, void* d_ws, size_t ws_size, hipStream_t stream) {
  char* p = (char*)d_ws;
  auto take = [&](size_t b) {
    char* r = p;
    p += (b + 255) & ~(size_t)255;
    return r;
  };
  int* deg      = (int*)take((size_t)N_NODES * 4);
  int* row_ptr  = (int*)take((size_t)(N_NODES + 4) * 4);
  int* cursor   = (int*)take((size_t)N_NODES * 4);
  int* esrc     = (int*)take((size_t)N_EDGES * 4);
  int* bsum     = (int*)take(256 * 4);
  int* boffb    = (int*)take(256 * 4);
  unsigned short* W1T = (unsigned short*)take((size_t)512 * 128 * 2);
  unsigned short* W2T = (unsigned short*)take((size_t)512 * 1024 * 2);
  unsigned short* W3T = (unsigned short*)take((size_t)512 * 1024 * 2);
  unsigned short* W4T = (unsigned short*)take((size_t)256 * 512 * 2);  // [Wl4^T;Wr4^T]
  float* ssum   = (float*)take(512 * 4);
  float* ssq    = (float*)take(512 * 4);
  float* scale  = (float*)take(512 * 4);
  float* shiftv = (float*)take(512 * 4);
  unsigned short* abuf = (unsigned short*)take((size_t)M_PAD * 512 * 2);
  unsigned short* ybuf = (unsigned short*)take((size_t)M_PAD * 512 * 2);
  unsigned short* hbuf = (unsigned short*)take((size_t)M_PAD * 512 * 2);

  size_t need = (size_t)(p - (char*)d_ws);
  if (need > ws_size || n_in < 20) {
    hipMemsetAsync(d_out, 0, (size_t)out_size * 4, stream);
    return;
  }

  const float* x   = (const float*)d_in[0];
  const int*   ei  = (const int*)d_in[1];
  const int*   srcv = ei;
  const int*   dstv = ei + N_EDGES;
  const float* Wl1 = (const float*)d_in[2];
  const float* bl1 = (const float*)d_in[3];
  const float* Wr1 = (const float*)d_in[4];
  const float* Wl2 = (const float*)d_in[5];
  const float* bl2 = (const float*)d_in[6];
  const float* Wr2 = (const float*)d_in[7];
  const float* Wl3 = (const float*)d_in[8];
  const float* bl3 = (const float*)d_in[9];
  const float* Wr3 = (const float*)d_in[10];
  const float* Wl4 = (const float*)d_in[11];
  const float* bl4 = (const float*)d_in[12];
  const float* Wr4 = (const float*)d_in[13];
  const float* g1  = (const float*)d_in[14];
  const float* b1  = (const float*)d_in[15];
  const float* g2  = (const float*)d_in[16];
  const float* b2  = (const float*)d_in[17];
  const float* g3  = (const float*)d_in[18];
  const float* b3  = (const float*)d_in[19];

  // CSR (parallel scan)
  hipMemsetAsync(deg, 0, (size_t)N_NODES * 4, stream);
  count_deg<<<(N_EDGES + 255) / 256, 256, 0, stream>>>(dstv, deg);
  block_sums<<<SCAN_B, 256, 0, stream>>>(deg, bsum);
  scan_bsums<<<1, 256, 0, stream>>>(bsum, boffb);
  write_rowptr<<<SCAN_B, 256, 0, stream>>>(deg, boffb, row_ptr, cursor);
  scatter_edges<<<(N_EDGES + 255) / 256, 256, 0, stream>>>(srcv, dstv, cursor, esrc);

  // weights
  pack_wt<<<(512 * 128 + 255) / 256, 256, 0, stream>>>(Wl1, Wr1, W1T, 50, 512, 512, 128);
  pack_wt<<<(512 * 1024 + 255) / 256, 256, 0, stream>>>(Wl2, Wr2, W2T, 512, 512, 512, 1024);
  pack_wt<<<(512 * 1024 + 255) / 256, 256, 0, stream>>>(Wl3, Wr3, W3T, 512, 512, 512, 1024);
  pack_w1<<<(128 * 512 + 255) / 256, 256, 0, stream>>>(Wl4, W4T, 512, 121, 128, 512);
  pack_w1<<<(128 * 512 + 255) / 256, 256, 0, stream>>>(Wr4, W4T + 128 * 512, 512, 121, 128, 512);

  dim3 gemm_grid(4, 391);  // x = N-block (fast) -> A-panel reuse in L2
  int bn_blocks = (int)(((long)M_PAD * 512 / 8) / 256);

  // ---- layer 1 ----
  prep1v<<<M_PAD, 256, 0, stream>>>(x, row_ptr, esrc, abuf);
  hipMemsetAsync(ssum, 0, 512 * 4, stream);
  hipMemsetAsync(ssq, 0, 512 * 4, stream);
  gemm_bf16<0><<<gemm_grid, 256, 0, stream>>>(abuf, abuf, 128, 128, W1T, 128, bl1, ybuf, 512,
                                              nullptr, ssum, ssq);
  bn_finalize<<<1, 512, 0, stream>>>(ssum, ssq, g1, b1, scale, shiftv);
  bn_relu<<<bn_blocks, 256, 0, stream>>>(ybuf, scale, shiftv, hbuf);

  // ---- layer 2 ----
  agg_mean512<<<M_PAD, 256, 0, stream>>>(row_ptr, esrc, hbuf, abuf);
  hipMemsetAsync(ssum, 0, 512 * 4, stream);
  hipMemsetAsync(ssq, 0, 512 * 4, stream);
  gemm_bf16<0><<<gemm_grid, 256, 0, stream>>>(abuf, hbuf, 512, 512, W2T, 1024, bl2, ybuf, 512,
                                              nullptr, ssum, ssq);
  bn_finalize<<<1, 512, 0, stream>>>(ssum, ssq, g2, b2, scale, shiftv);
  bn_relu<<<bn_blocks, 256, 0, stream>>>(ybuf, scale, shiftv, hbuf);

  // ---- layer 3 ----
  agg_mean512<<<M_PAD, 256, 0, stream>>>(row_ptr, esrc, hbuf, abuf);
  hipMemsetAsync(ssum, 0, 512 * 4, stream);
  hipMemsetAsync(ssq, 0, 512 * 4, stream);
  gemm_bf16<0><<<gemm_grid, 256, 0, stream>>>(abuf, hbuf, 512, 512, W3T, 1024, bl3, ybuf, 512,
                                              nullptr, ssum, ssq);
  bn_finalize<<<1, 512, 0, stream>>>(ssum, ssq, g3, b3, scale, shiftv);
  bn_relu<<<bn_blocks, 256, 0, stream>>>(ybuf, scale, shiftv, hbuf);

  // ---- layer 4: single GEMM, split epilogue: t4=h3@Wl4 (bf16) | d_out=h3@Wr4+bl4 (f32) ----
  gemm_bf16<1><<<dim3(2, 391), 256, 0, stream>>>(hbuf, hbuf, 512, 512, W4T, 512, bl4, ybuf, 128,
                                                 (float*)d_out, nullptr, nullptr);
  agg_add121<<<(N_NODES + 3) / 4, 256, 0, stream>>>(row_ptr, esrc, ybuf, (float*)d_out);
}

// Round 7
// 702.626 us; speedup vs baseline: 1.7607x; 1.0167x over previous
//
#include <hip/hip_runtime.h>

#define N_NODES 50000
#define N_EDGES 400000
#define M_PAD   50048   // 391 * 128
#define SCAN_B  196     // ceil(N_NODES/256)
#define EPS_BN  1e-5f

typedef short bf16x8 __attribute__((ext_vector_type(8)));
typedef float f32x4 __attribute__((ext_vector_type(4)));

__device__ __forceinline__ float bf2f(unsigned short h) {
  union { unsigned int u; float f; } v; v.u = ((unsigned int)h) << 16; return v.f;
}
__device__ __forceinline__ unsigned short f2bf(float x) {
  union { float f; unsigned int u; } v; v.f = x;
  unsigned int r = v.u + 0x7FFFu + ((v.u >> 16) & 1u);
  return (unsigned short)(r >> 16);
}

// ---------------- CSR build ----------------
__global__ void count_deg(const int* __restrict__ dst, int* __restrict__ deg) {
  int e = blockIdx.x * 256 + threadIdx.x;
  if (e < N_EDGES) {
    int d = dst[e];
    if (d >= 0 && d < N_NODES) atomicAdd(&deg[d], 1);
  }
}

__global__ void block_sums(const int* __restrict__ deg, int* __restrict__ bsum) {
  __shared__ int sd[256];
  int b = blockIdx.x, t = threadIdx.x;
  int i = b * 256 + t;
  sd[t] = (i < N_NODES) ? deg[i] : 0;
  __syncthreads();
  for (int off = 128; off > 0; off >>= 1) {
    if (t < off) sd[t] += sd[t + off];
    __syncthreads();
  }
  if (t == 0) bsum[b] = sd[0];
}

__global__ void scan_bsums(const int* __restrict__ bsum, int* __restrict__ boff) {
  __shared__ int sd[256];
  int t = threadIdx.x;
  int v = (t < SCAN_B) ? bsum[t] : 0;
  sd[t] = v;
  __syncthreads();
  for (int off = 1; off < 256; off <<= 1) {
    int add = (t >= off) ? sd[t - off] : 0;
    __syncthreads();
    sd[t] += add;
    __syncthreads();
  }
  if (t < SCAN_B) boff[t] = sd[t] - v;  // exclusive
}

__global__ void write_rowptr(const int* __restrict__ deg, const int* __restrict__ boff,
                             int* __restrict__ row_ptr, int* __restrict__ cursor) {
  __shared__ int sd[256];
  int b = blockIdx.x, t = threadIdx.x;
  int i = b * 256 + t;
  int v = (i < N_NODES) ? deg[i] : 0;
  sd[t] = v;
  __syncthreads();
  for (int off = 1; off < 256; off <<= 1) {
    int add = (t >= off) ? sd[t - off] : 0;
    __syncthreads();
    sd[t] += add;
    __syncthreads();
  }
  if (i < N_NODES) {
    int ex = boff[b] + sd[t] - v;
    row_ptr[i] = ex;
    cursor[i]  = ex;
    if (i == N_NODES - 1) row_ptr[N_NODES] = boff[b] + sd[t];
  }
}

__global__ void scatter_edges(const int* __restrict__ src, const int* __restrict__ dst,
                              int* __restrict__ cursor, int* __restrict__ esrc) {
  int e = blockIdx.x * 256 + threadIdx.x;
  if (e < N_EDGES) {
    int d = dst[e];
    int s = src[e];
    if (d >= 0 && d < N_NODES && s >= 0 && s < N_NODES) {
      int p = atomicAdd(&cursor[d], 1);
      esrc[p] = s;
    }
  }
}

// ---------------- weight packs ----------------
__global__ void pack_wt(const float* __restrict__ Wl, const float* __restrict__ Wr,
                        unsigned short* __restrict__ WT, int Keach, int N, int Npad, int Kpad) {
  int idx = blockIdx.x * 256 + threadIdx.x;
  if (idx >= Npad * Kpad) return;
  int n = idx / Kpad, k = idx % Kpad;
  float v = 0.f;
  if (n < N) {
    if (k < Keach) v = Wl[k * N + n];
    else if (k < 2 * Keach) v = Wr[(k - Keach) * N + n];
  }
  WT[idx] = f2bf(v);
}

__global__ void pack_w1(const float* __restrict__ W, unsigned short* __restrict__ WT, int K,
                        int N, int Npad, int Kpad) {
  int idx = blockIdx.x * 256 + threadIdx.x;
  if (idx >= Npad * Kpad) return;
  int n = idx / Kpad, k = idx % Kpad;
  float v = (n < N && k < K) ? W[k * N + n] : 0.f;
  WT[idx] = f2bf(v);
}

// ---------------- layer-1 input build ----------------
__global__ void prep1v(const float* __restrict__ x, const int* __restrict__ row_ptr,
                       const int* __restrict__ esrc, unsigned short* __restrict__ cat1) {
  __shared__ float part[4][64];
  int n = blockIdx.x, t = threadIdx.x;
  int w = t >> 6, lane = t & 63;
  unsigned short* row = cat1 + (long)n * 128;
  if (n >= N_NODES) {
    if (t < 64) { row[t] = 0; row[64 + t] = 0; }
    return;
  }
  int e0 = row_ptr[n], e1 = row_ptr[n + 1];
  float acc = 0.f;
  if (lane < 50) {
    for (int e = e0 + w; e < e1; e += 4) acc += x[(long)esrc[e] * 50 + lane];
  }
  part[w][lane] = acc;
  __syncthreads();
  if (t < 128) {
    if (t < 64) {
      float s = part[0][t] + part[1][t] + part[2][t] + part[3][t];
      float rdeg = (e1 > e0) ? 1.f / (float)(e1 - e0) : 0.f;
      if (t < 50) {
        row[t]      = f2bf(s * rdeg);
        row[50 + t] = f2bf(x[(long)n * 50 + t]);
      }
    } else if (t >= 100) {
      row[t] = 0;
    }
  }
}

// ---------------- mean aggregation, 512 cols ----------------
__global__ void agg_mean512(const int* __restrict__ row_ptr, const int* __restrict__ esrc,
                            const unsigned short* __restrict__ h,
                            unsigned short* __restrict__ agg) {
  __shared__ float part[4][512];
  int n = blockIdx.x, t = threadIdx.x;
  int w = t >> 6, lane = t & 63;
  unsigned int* outw = (unsigned int*)(agg + (long)n * 512);
  if (n >= N_NODES) { outw[t] = 0; return; }
  int e0 = row_ptr[n], e1 = row_ptr[n + 1];
  float acc[8] = {0.f, 0.f, 0.f, 0.f, 0.f, 0.f, 0.f, 0.f};
  for (int e = e0 + w; e < e1; e += 4) {
    int s = esrc[e];
    uint4 v = *(const uint4*)(h + (long)s * 512 + lane * 8);
    const unsigned short* pv = (const unsigned short*)&v;
#pragma unroll
    for (int j = 0; j < 8; ++j) acc[j] += bf2f(pv[j]);
  }
  float* pw = &part[w][lane * 8];
#pragma unroll
  for (int j = 0; j < 8; ++j) pw[j] = acc[j];
  __syncthreads();
  int c = t * 2;
  float s0 = part[0][c] + part[1][c] + part[2][c] + part[3][c];
  float s1 = part[0][c + 1] + part[1][c + 1] + part[2][c + 1] + part[3][c + 1];
  float rdeg = (e1 > e0) ? 1.f / (float)(e1 - e0) : 0.f;
  unsigned int pk = (unsigned int)f2bf(s0 * rdeg) | ((unsigned int)f2bf(s1 * rdeg) << 16);
  outw[t] = pk;
}

// ---------------- layer-4 gather-add, 121 cols ----------------
__global__ void agg_add121(const int* __restrict__ row_ptr, const int* __restrict__ esrc,
                           const unsigned short* __restrict__ t4, float* __restrict__ out) {
  int n = blockIdx.x * 4 + (threadIdx.x >> 6);
  if (n >= N_NODES) return;
  int lane = threadIdx.x & 63;
  int g = lane >> 4;
  int cl = lane & 15;
  int e0 = row_ptr[n], e1 = row_ptr[n + 1];
  float acc[8] = {0.f, 0.f, 0.f, 0.f, 0.f, 0.f, 0.f, 0.f};
  for (int e = e0 + g; e < e1; e += 4) {
    int s = esrc[e];
    uint4 v = *(const uint4*)(t4 + (long)s * 128 + cl * 8);
    const unsigned short* pv = (const unsigned short*)&v;
#pragma unroll
    for (int j = 0; j < 8; ++j) acc[j] += bf2f(pv[j]);
  }
#pragma unroll
  for (int j = 0; j < 8; ++j) {
    acc[j] += __shfl_xor(acc[j], 16);
    acc[j] += __shfl_xor(acc[j], 32);
  }
  if (g == 0) {
    float rdeg = (e1 > e0) ? 1.f / (float)(e1 - e0) : 0.f;
#pragma unroll
    for (int j = 0; j < 8; ++j) {
      int c = cl * 8 + j;
      if (c < 121) out[(long)n * 121 + c] += acc[j] * rdeg;
    }
  }
}

// ---------------- BN finalize / apply+ReLU ----------------
__global__ void bn_finalize(const float* __restrict__ ssum, const float* __restrict__ ssq,
                            const float* __restrict__ g, const float* __restrict__ b,
                            float* __restrict__ scale, float* __restrict__ shiftv) {
  int c = threadIdx.x;
  float mu  = ssum[c] * (1.f / N_NODES);
  float var = ssq[c] * (1.f / N_NODES) - mu * mu;
  float rs  = rsqrtf(var + EPS_BN);
  float sc  = g[c] * rs;
  scale[c]  = sc;
  shiftv[c] = b[c] - mu * sc;
}

__global__ void bn_relu(const unsigned short* __restrict__ y, const float* __restrict__ scale,
                        const float* __restrict__ shiftv, unsigned short* __restrict__ hout) {
  long idx = ((long)blockIdx.x * 256 + threadIdx.x) * 8;
  if (idx >= (long)M_PAD * 512) return;
  int row = (int)(idx >> 9);
  int col = (int)(idx & 511);
  unsigned short* o = hout + idx;
  if (row >= N_NODES) {
    uint4 z; z.x = 0; z.y = 0; z.z = 0; z.w = 0;
    *(uint4*)o = z;
    return;
  }
  uint4 v = *(const uint4*)(y + idx);
  unsigned short* p = (unsigned short*)&v;
  uint4 rr;
  unsigned short* q = (unsigned short*)&rr;
#pragma unroll
  for (int j = 0; j < 8; ++j) {
    float f = bf2f(p[j]) * scale[col + j] + shiftv[col + j];
    q[j] = f2bf(fmaxf(f, 0.f));
  }
  *(uint4*)o = rr;
}

// ---------------- bf16 MFMA GEMM, 1D grid + bijective XCD-chunk swizzle (m204) --------
// Logical id wg: bm = wg / nblk (M-panel), bn = wg % nblk (N-block). All nblk N-blocks of
// an M-panel are logically consecutive -> land on the SAME XCD -> A-panel fetched once/L2.
// MODE 0: bf16 out (+bias) with fused BN-stats epilogue (layers 1-3)
// MODE 1: layer-4 split epilogue: cols 0..127 -> bf16 t4 (no bias), 128..248 -> f32 out+bias
__device__ __forceinline__ void gl_lds16(const void* g, void* l) {
  __builtin_amdgcn_global_load_lds((const __attribute__((address_space(1))) unsigned int*)g,
                                   (__attribute__((address_space(3))) unsigned int*)l, 16, 0, 0);
}

template <int MODE>
__global__ void gemm_bf16(int nblk, const unsigned short* __restrict__ A0,
                          const unsigned short* __restrict__ A1, int lda, int KA0,
                          const unsigned short* __restrict__ BT, int K,
                          const float* __restrict__ bias, unsigned short* __restrict__ outb,
                          int ldob, float* __restrict__ outf, float* __restrict__ ssum,
                          float* __restrict__ ssq) {
  __shared__ __align__(16) unsigned short As[128 * 64];
  __shared__ __align__(16) unsigned short Bs[128 * 64];

  // bijective XCD swizzle: hardware round-robins linear id % 8 across XCDs
  const int nwg  = gridDim.x;
  const int orig = blockIdx.x;
  const int xcd  = orig & 7;
  const int idx  = orig >> 3;
  const int q    = nwg >> 3, r = nwg & 7;
  const int wg   = ((xcd < r) ? xcd * (q + 1) : r * (q + 1) + (xcd - r) * q) + idx;
  const int bm   = wg / nblk;
  const int bn   = wg - bm * nblk;

  const int t    = threadIdx.x;
  const int lane = t & 63;
  const int wave = t >> 6;
  const long brow = (long)bm * 128;
  const int  bcol = bn * 128;
  const int  wr   = (wave >> 1) * 64;
  const int  wc   = (wave & 1) * 64;

  f32x4 acc[4][4] = {};

  const long aoff = (brow + (t >> 3)) * (long)lda + ((t & 7) * 8);
  const long boff = ((long)(bcol + (t >> 3))) * K + ((t & 7) * 8);
  unsigned short* al0 = As + t * 8;
  unsigned short* bl0 = Bs + t * 8;

  for (int k0 = 0; k0 < K; k0 += 64) {
    const unsigned short* ag = ((k0 < KA0) ? (A0 + k0) : (A1 + (k0 - KA0))) + aoff;
    const unsigned short* bg = BT + boff + k0;
#pragma unroll
    for (int rr = 0; rr < 4; ++rr) {
      gl_lds16(ag + (long)rr * 32 * lda, al0 + rr * 2048);
      gl_lds16(bg + (long)rr * 32 * K, bl0 + rr * 2048);
    }
    __syncthreads();
    const unsigned short* ab = As + (wr + (lane & 15)) * 64 + ((lane >> 4) * 8);
    const unsigned short* bb = Bs + (wc + (lane & 15)) * 64 + ((lane >> 4) * 8);
#pragma unroll
    for (int kk = 0; kk < 64; kk += 32) {
      bf16x8 af[4], bfr[4];
#pragma unroll
      for (int m = 0; m < 4; ++m) af[m] = *(const bf16x8*)(ab + m * 16 * 64 + kk);
#pragma unroll
      for (int n = 0; n < 4; ++n) bfr[n] = *(const bf16x8*)(bb + n * 16 * 64 + kk);
#pragma unroll
      for (int m = 0; m < 4; ++m)
#pragma unroll
        for (int n = 0; n < 4; ++n)
          acc[m][n] = __builtin_amdgcn_mfma_f32_16x16x32_bf16(af[m], bfr[n], acc[m][n], 0, 0, 0);
    }
    __syncthreads();
  }

  float* sstat = (float*)As;  // reuse As for stats reduction
  if (MODE == 0) {
    if (t < 128) { sstat[t] = 0.f; sstat[128 + t] = 0.f; }
    __syncthreads();
  }

#pragma unroll
  for (int m = 0; m < 4; ++m) {
    int row0 = (int)brow + wr + m * 16 + (lane >> 4) * 4;
#pragma unroll
    for (int n = 0; n < 4; ++n) {
      int col = bcol + wc + n * 16 + (lane & 15);
      if (MODE == 0) {
        float bs = bias[col];
#pragma unroll
        for (int j = 0; j < 4; ++j)
          outb[(long)(row0 + j) * ldob + col] = f2bf(acc[m][n][j] + bs);
      } else {
        if (col < 128) {
#pragma unroll
          for (int j = 0; j < 4; ++j)
            outb[(long)(row0 + j) * ldob + col] = f2bf(acc[m][n][j]);
        } else {
          int c2 = col - 128;
          if (c2 < 121) {
            float bs = bias[c2];
#pragma unroll
            for (int j = 0; j < 4; ++j) {
              int row = row0 + j;
              if (row < N_NODES) outf[(long)row * 121 + c2] = acc[m][n][j] + bs;
            }
          }
        }
      }
    }
  }

  if (MODE == 0) {
#pragma unroll
    for (int n = 0; n < 4; ++n) {
      int colL = wc + n * 16 + (lane & 15);
      float bs = bias[bcol + colL];
      float s = 0.f, s2 = 0.f;
#pragma unroll
      for (int m = 0; m < 4; ++m) {
        int row0 = (int)brow + wr + m * 16 + (lane >> 4) * 4;
#pragma unroll
        for (int j = 0; j < 4; ++j) {
          if (row0 + j < N_NODES) {
            float v = acc[m][n][j] + bs;
            s += v;
            s2 += v * v;
          }
        }
      }
      atomicAdd(&sstat[colL], s);
      atomicAdd(&sstat[128 + colL], s2);
    }
    __syncthreads();
    if (t < 128) {
      atomicAdd(&ssum[bcol + t], sstat[t]);
      atomicAdd(&ssq[bcol + t], sstat[128 + t]);
    }
  }
}

// ---------------- host launcher ----------------
extern "C" void kernel_launch(void* const* d_in, const int* in_sizes, int n_in, void* d_out,
                              int out_size, void* d_ws, size_t ws_size, hipStream_t stream) {
  char* p = (char*)d_ws;
  auto take = [&](size_t b) {
    char* r = p;
    p += (b + 255) & ~(size_t)255;
    return r;
  };
  int* deg      = (int*)take((size_t)N_NODES * 4);
  int* row_ptr  = (int*)take((size_t)(N_NODES + 4) * 4);
  int* cursor   = (int*)take((size_t)N_NODES * 4);
  int* esrc     = (int*)take((size_t)N_EDGES * 4);
  int* bsum     = (int*)take(256 * 4);
  int* boffb    = (int*)take(256 * 4);
  unsigned short* W1T = (unsigned short*)take((size_t)512 * 128 * 2);
  unsigned short* W2T = (unsigned short*)take((size_t)512 * 1024 * 2);
  unsigned short* W3T = (unsigned short*)take((size_t)512 * 1024 * 2);
  unsigned short* W4T = (unsigned short*)take((size_t)256 * 512 * 2);  // [Wl4^T;Wr4^T]
  float* ssum   = (float*)take(512 * 4);
  float* ssq    = (float*)take(512 * 4);
  float* scale  = (float*)take(512 * 4);
  float* shiftv = (float*)take(512 * 4);
  unsigned short* abuf = (unsigned short*)take((size_t)M_PAD * 512 * 2);
  unsigned short* ybuf = (unsigned short*)take((size_t)M_PAD * 512 * 2);
  unsigned short* hbuf = (unsigned short*)take((size_t)M_PAD * 512 * 2);

  size_t need = (size_t)(p - (char*)d_ws);
  if (need > ws_size || n_in < 20) {
    hipMemsetAsync(d_out, 0, (size_t)out_size * 4, stream);
    return;
  }

  const float* x   = (const float*)d_in[0];
  const int*   ei  = (const int*)d_in[1];
  const int*   srcv = ei;
  const int*   dstv = ei + N_EDGES;
  const float* Wl1 = (const float*)d_in[2];
  const float* bl1 = (const float*)d_in[3];
  const float* Wr1 = (const float*)d_in[4];
  const float* Wl2 = (const float*)d_in[5];
  const float* bl2 = (const float*)d_in[6];
  const float* Wr2 = (const float*)d_in[7];
  const float* Wl3 = (const float*)d_in[8];
  const float* bl3 = (const float*)d_in[9];
  const float* Wr3 = (const float*)d_in[10];
  const float* Wl4 = (const float*)d_in[11];
  const float* bl4 = (const float*)d_in[12];
  const float* Wr4 = (const float*)d_in[13];
  const float* g1  = (const float*)d_in[14];
  const float* b1  = (const float*)d_in[15];
  const float* g2  = (const float*)d_in[16];
  const float* b2  = (const float*)d_in[17];
  const float* g3  = (const float*)d_in[18];
  const float* b3  = (const float*)d_in[19];

  // CSR (parallel scan)
  hipMemsetAsync(deg, 0, (size_t)N_NODES * 4, stream);
  count_deg<<<(N_EDGES + 255) / 256, 256, 0, stream>>>(dstv, deg);
  block_sums<<<SCAN_B, 256, 0, stream>>>(deg, bsum);
  scan_bsums<<<1, 256, 0, stream>>>(bsum, boffb);
  write_rowptr<<<SCAN_B, 256, 0, stream>>>(deg, boffb, row_ptr, cursor);
  scatter_edges<<<(N_EDGES + 255) / 256, 256, 0, stream>>>(srcv, dstv, cursor, esrc);

  // weights
  pack_wt<<<(512 * 128 + 255) / 256, 256, 0, stream>>>(Wl1, Wr1, W1T, 50, 512, 512, 128);
  pack_wt<<<(512 * 1024 + 255) / 256, 256, 0, stream>>>(Wl2, Wr2, W2T, 512, 512, 512, 1024);
  pack_wt<<<(512 * 1024 + 255) / 256, 256, 0, stream>>>(Wl3, Wr3, W3T, 512, 512, 512, 1024);
  pack_w1<<<(128 * 512 + 255) / 256, 256, 0, stream>>>(Wl4, W4T, 512, 121, 128, 512);
  pack_w1<<<(128 * 512 + 255) / 256, 256, 0, stream>>>(Wr4, W4T + 128 * 512, 512, 121, 128, 512);

  int gemm_nwg = 4 * 391;  // 1D grid, swizzled in-kernel
  int bn_blocks = (int)(((long)M_PAD * 512 / 8) / 256);

  // ---- layer 1 ----
  prep1v<<<M_PAD, 256, 0, stream>>>(x, row_ptr, esrc, abuf);
  hipMemsetAsync(ssum, 0, 512 * 4, stream);
  hipMemsetAsync(ssq, 0, 512 * 4, stream);
  gemm_bf16<0><<<gemm_nwg, 256, 0, stream>>>(4, abuf, abuf, 128, 128, W1T, 128, bl1, ybuf, 512,
                                             nullptr, ssum, ssq);
  bn_finalize<<<1, 512, 0, stream>>>(ssum, ssq, g1, b1, scale, shiftv);
  bn_relu<<<bn_blocks, 256, 0, stream>>>(ybuf, scale, shiftv, hbuf);

  // ---- layer 2 ----
  agg_mean512<<<M_PAD, 256, 0, stream>>>(row_ptr, esrc, hbuf, abuf);
  hipMemsetAsync(ssum, 0, 512 * 4, stream);
  hipMemsetAsync(ssq, 0, 512 * 4, stream);
  gemm_bf16<0><<<gemm_nwg, 256, 0, stream>>>(4, abuf, hbuf, 512, 512, W2T, 1024, bl2, ybuf, 512,
                                             nullptr, ssum, ssq);
  bn_finalize<<<1, 512, 0, stream>>>(ssum, ssq, g2, b2, scale, shiftv);
  bn_relu<<<bn_blocks, 256, 0, stream>>>(ybuf, scale, shiftv, hbuf);

  // ---- layer 3 ----
  agg_mean512<<<M_PAD, 256, 0, stream>>>(row_ptr, esrc, hbuf, abuf);
  hipMemsetAsync(ssum, 0, 512 * 4, stream);
  hipMemsetAsync(ssq, 0, 512 * 4, stream);
  gemm_bf16<0><<<gemm_nwg, 256, 0, stream>>>(4, abuf, hbuf, 512, 512, W3T, 1024, bl3, ybuf, 512,
                                             nullptr, ssum, ssq);
  bn_finalize<<<1, 512, 0, stream>>>(ssum, ssq, g3, b3, scale, shiftv);
  bn_relu<<<bn_blocks, 256, 0, stream>>>(ybuf, scale, shiftv, hbuf);

  // ---- layer 4: single GEMM, split epilogue: t4=h3@Wl4 (bf16) | d_out=h3@Wr4+bl4 (f32) ----
  gemm_bf16<1><<<2 * 391, 256, 0, stream>>>(2, hbuf, hbuf, 512, 512, W4T, 512, bl4, ybuf, 128,
                                            (float*)d_out, nullptr, nullptr);
  agg_add121<<<(N_NODES + 3) / 4, 256, 0, stream>>>(row_ptr, esrc, ybuf, (float*)d_out);
}

// Round 8
// 677.617 us; speedup vs baseline: 1.8257x; 1.0369x over previous
//
#include <hip/hip_runtime.h>

#define N_NODES 50000
#define N_EDGES 400000
#define M_PAD   50176   // 196 * 256
#define SCAN_B  196
#define EPS_BN  1e-5f

typedef short bf16x8 __attribute__((ext_vector_type(8)));
typedef float f32x4 __attribute__((ext_vector_type(4)));

__device__ __forceinline__ float bf2f(unsigned short h) {
  union { unsigned int u; float f; } v; v.u = ((unsigned int)h) << 16; return v.f;
}
__device__ __forceinline__ unsigned short f2bf(float x) {
  union { float f; unsigned int u; } v; v.f = x;
  unsigned int r = v.u + 0x7FFFu + ((v.u >> 16) & 1u);
  return (unsigned short)(r >> 16);
}

// ---------------- CSR build ----------------
__global__ void count_deg(const int* __restrict__ dst, int* __restrict__ deg) {
  int e = blockIdx.x * 256 + threadIdx.x;
  if (e < N_EDGES) {
    int d = dst[e];
    if (d >= 0 && d < N_NODES) atomicAdd(&deg[d], 1);
  }
}

__global__ void block_sums(const int* __restrict__ deg, int* __restrict__ bsum) {
  __shared__ int sd[256];
  int b = blockIdx.x, t = threadIdx.x;
  int i = b * 256 + t;
  sd[t] = (i < N_NODES) ? deg[i] : 0;
  __syncthreads();
  for (int off = 128; off > 0; off >>= 1) {
    if (t < off) sd[t] += sd[t + off];
    __syncthreads();
  }
  if (t == 0) bsum[b] = sd[0];
}

__global__ void scan_bsums(const int* __restrict__ bsum, int* __restrict__ boff) {
  __shared__ int sd[256];
  int t = threadIdx.x;
  int v = (t < SCAN_B) ? bsum[t] : 0;
  sd[t] = v;
  __syncthreads();
  for (int off = 1; off < 256; off <<= 1) {
    int add = (t >= off) ? sd[t - off] : 0;
    __syncthreads();
    sd[t] += add;
    __syncthreads();
  }
  if (t < SCAN_B) boff[t] = sd[t] - v;  // exclusive
}

__global__ void write_rowptr(const int* __restrict__ deg, const int* __restrict__ boff,
                             int* __restrict__ row_ptr, int* __restrict__ cursor) {
  __shared__ int sd[256];
  int b = blockIdx.x, t = threadIdx.x;
  int i = b * 256 + t;
  int v = (i < N_NODES) ? deg[i] : 0;
  sd[t] = v;
  __syncthreads();
  for (int off = 1; off < 256; off <<= 1) {
    int add = (t >= off) ? sd[t - off] : 0;
    __syncthreads();
    sd[t] += add;
    __syncthreads();
  }
  if (i < N_NODES) {
    int ex = boff[b] + sd[t] - v;
    row_ptr[i] = ex;
    cursor[i]  = ex;
    if (i == N_NODES - 1) row_ptr[N_NODES] = boff[b] + sd[t];
  }
}

__global__ void scatter_edges(const int* __restrict__ src, const int* __restrict__ dst,
                              int* __restrict__ cursor, int* __restrict__ esrc) {
  int e = blockIdx.x * 256 + threadIdx.x;
  if (e < N_EDGES) {
    int d = dst[e];
    int s = src[e];
    if (d >= 0 && d < N_NODES && s >= 0 && s < N_NODES) {
      int p = atomicAdd(&cursor[d], 1);
      esrc[p] = s;
    }
  }
}

// ---------------- weight packs ----------------
__global__ void pack_wt(const float* __restrict__ Wl, const float* __restrict__ Wr,
                        unsigned short* __restrict__ WT, int Keach, int N, int Npad, int Kpad) {
  int idx = blockIdx.x * 256 + threadIdx.x;
  if (idx >= Npad * Kpad) return;
  int n = idx / Kpad, k = idx % Kpad;
  float v = 0.f;
  if (n < N) {
    if (k < Keach) v = Wl[k * N + n];
    else if (k < 2 * Keach) v = Wr[(k - Keach) * N + n];
  }
  WT[idx] = f2bf(v);
}

__global__ void pack_w1(const float* __restrict__ W, unsigned short* __restrict__ WT, int K,
                        int N, int Npad, int Kpad) {
  int idx = blockIdx.x * 256 + threadIdx.x;
  if (idx >= Npad * Kpad) return;
  int n = idx / Kpad, k = idx % Kpad;
  float v = (n < N && k < K) ? W[k * N + n] : 0.f;
  WT[idx] = f2bf(v);
}

// ---------------- layer-1 input build ----------------
__global__ void prep1v(const float* __restrict__ x, const int* __restrict__ row_ptr,
                       const int* __restrict__ esrc, unsigned short* __restrict__ cat1) {
  __shared__ float part[4][64];
  int n = blockIdx.x, t = threadIdx.x;
  int w = t >> 6, lane = t & 63;
  unsigned short* row = cat1 + (long)n * 128;
  if (n >= N_NODES) {
    if (t < 64) { row[t] = 0; row[64 + t] = 0; }
    return;
  }
  int e0 = row_ptr[n], e1 = row_ptr[n + 1];
  float acc = 0.f;
  if (lane < 50) {
    for (int e = e0 + w; e < e1; e += 4) acc += x[(long)esrc[e] * 50 + lane];
  }
  part[w][lane] = acc;
  __syncthreads();
  if (t < 128) {
    if (t < 64) {
      float s = part[0][t] + part[1][t] + part[2][t] + part[3][t];
      float rdeg = (e1 > e0) ? 1.f / (float)(e1 - e0) : 0.f;
      if (t < 50) {
        row[t]      = f2bf(s * rdeg);
        row[50 + t] = f2bf(x[(long)n * 50 + t]);
      }
    } else if (t >= 100) {
      row[t] = 0;
    }
  }
}

// ---------------- mean aggregation, 512 cols ----------------
__global__ void agg_mean512(const int* __restrict__ row_ptr, const int* __restrict__ esrc,
                            const unsigned short* __restrict__ h,
                            unsigned short* __restrict__ agg) {
  __shared__ float part[4][512];
  int n = blockIdx.x, t = threadIdx.x;
  int w = t >> 6, lane = t & 63;
  unsigned int* outw = (unsigned int*)(agg + (long)n * 512);
  if (n >= N_NODES) { outw[t] = 0; return; }
  int e0 = row_ptr[n], e1 = row_ptr[n + 1];
  float acc[8] = {0.f, 0.f, 0.f, 0.f, 0.f, 0.f, 0.f, 0.f};
  for (int e = e0 + w; e < e1; e += 4) {
    int s = esrc[e];
    uint4 v = *(const uint4*)(h + (long)s * 512 + lane * 8);
    const unsigned short* pv = (const unsigned short*)&v;
#pragma unroll
    for (int j = 0; j < 8; ++j) acc[j] += bf2f(pv[j]);
  }
  float* pw = &part[w][lane * 8];
#pragma unroll
  for (int j = 0; j < 8; ++j) pw[j] = acc[j];
  __syncthreads();
  int c = t * 2;
  float s0 = part[0][c] + part[1][c] + part[2][c] + part[3][c];
  float s1 = part[0][c + 1] + part[1][c + 1] + part[2][c + 1] + part[3][c + 1];
  float rdeg = (e1 > e0) ? 1.f / (float)(e1 - e0) : 0.f;
  unsigned int pk = (unsigned int)f2bf(s0 * rdeg) | ((unsigned int)f2bf(s1 * rdeg) << 16);
  outw[t] = pk;
}

// ---------------- layer-4 gather-add, 121 cols ----------------
__global__ void agg_add121(const int* __restrict__ row_ptr, const int* __restrict__ esrc,
                           const unsigned short* __restrict__ t4, float* __restrict__ out) {
  int n = blockIdx.x * 4 + (threadIdx.x >> 6);
  if (n >= N_NODES) return;
  int lane = threadIdx.x & 63;
  int g = lane >> 4;
  int cl = lane & 15;
  int e0 = row_ptr[n], e1 = row_ptr[n + 1];
  float acc[8] = {0.f, 0.f, 0.f, 0.f, 0.f, 0.f, 0.f, 0.f};
  for (int e = e0 + g; e < e1; e += 4) {
    int s = esrc[e];
    uint4 v = *(const uint4*)(t4 + (long)s * 128 + cl * 8);
    const unsigned short* pv = (const unsigned short*)&v;
#pragma unroll
    for (int j = 0; j < 8; ++j) acc[j] += bf2f(pv[j]);
  }
#pragma unroll
  for (int j = 0; j < 8; ++j) {
    acc[j] += __shfl_xor(acc[j], 16);
    acc[j] += __shfl_xor(acc[j], 32);
  }
  if (g == 0) {
    float rdeg = (e1 > e0) ? 1.f / (float)(e1 - e0) : 0.f;
#pragma unroll
    for (int j = 0; j < 8; ++j) {
      int c = cl * 8 + j;
      if (c < 121) out[(long)n * 121 + c] += acc[j] * rdeg;
    }
  }
}

// ---------------- BN finalize / apply+ReLU ----------------
__global__ void bn_finalize(const float* __restrict__ ssum, const float* __restrict__ ssq,
                            const float* __restrict__ g, const float* __restrict__ b,
                            float* __restrict__ scale, float* __restrict__ shiftv) {
  int c = threadIdx.x;
  float mu  = ssum[c] * (1.f / N_NODES);
  float var = ssq[c] * (1.f / N_NODES) - mu * mu;
  float rs  = rsqrtf(var + EPS_BN);
  float sc  = g[c] * rs;
  scale[c]  = sc;
  shiftv[c] = b[c] - mu * sc;
}

__global__ void bn_relu(const unsigned short* __restrict__ y, const float* __restrict__ scale,
                        const float* __restrict__ shiftv, unsigned short* __restrict__ hout) {
  long idx = ((long)blockIdx.x * 256 + threadIdx.x) * 8;
  if (idx >= (long)M_PAD * 512) return;
  int row = (int)(idx >> 9);
  int col = (int)(idx & 511);
  unsigned short* o = hout + idx;
  if (row >= N_NODES) {
    uint4 z; z.x = 0; z.y = 0; z.z = 0; z.w = 0;
    *(uint4*)o = z;
    return;
  }
  uint4 v = *(const uint4*)(y + idx);
  unsigned short* p = (unsigned short*)&v;
  uint4 rr;
  unsigned short* q = (unsigned short*)&rr;
#pragma unroll
  for (int j = 0; j < 8; ++j) {
    float f = bf2f(p[j]) * scale[col + j] + shiftv[col + j];
    q[j] = f2bf(fmaxf(f, 0.f));
  }
  *(uint4*)o = rr;
}

// ---------------- 256x256 8-phase bf16 MFMA GEMM (T1+T2+T3min+T5) ----------------
// A row-major [M][lda] in two column-halves (A0: k<KA0, A1: k>=KA0); B as BT[N][K].
// 8 waves (2M x 4N), per-wave C = 128x64. LDS 128KB dynamic: A[2buf][2half][128][64],
// B same at +64KB. st-swizzle: byte_col ^= (row&7)<<4 (reads + pre-swizzled gl_lds source).
__device__ __forceinline__ void gl_lds16(const void* g, void* l) {
  __builtin_amdgcn_global_load_lds((const __attribute__((address_space(1))) unsigned int*)g,
                                   (__attribute__((address_space(3))) unsigned int*)l, 16, 0, 0);
}

__device__ __forceinline__ void stage_half(const unsigned short* srck, int ld, long row0,
                                           char* ldshalf, int q0) {
#pragma unroll
  for (int r = 0; r < 2; ++r) {
    int q = q0 + r * 8192;
    int row = q >> 7;
    int cus = ((q & 127) >> 1) ^ ((row & 7) << 3);  // inverse-swizzled source col (ushort)
    gl_lds16(srck + (row0 + row) * (long)ld + cus, ldshalf + q);
  }
}

__device__ __forceinline__ bf16x8 frag(const char* halfbase, int lr, int cb) {
  return *(const bf16x8*)(halfbase + lr * 128 + (cb ^ ((lr & 7) << 4)));
}

template <int MODE>
__launch_bounds__(512, 2)
__global__ void gemm256(int nblk, const unsigned short* __restrict__ A0,
                        const unsigned short* __restrict__ A1, int lda, int KA0,
                        const unsigned short* __restrict__ BT, int K,
                        const float* __restrict__ bias, unsigned short* __restrict__ outb,
                        int ldob, float* __restrict__ outf, float* __restrict__ ssum,
                        float* __restrict__ ssq) {
  extern __shared__ char smem[];

  // T1: bijective XCD-chunk swizzle
  const int nwg = gridDim.x, orig = blockIdx.x;
  const int xcd = orig & 7, sidx = orig >> 3;
  const int q8 = nwg >> 3, r8 = nwg & 7;
  const int wg = ((xcd < r8) ? xcd * (q8 + 1) : r8 * (q8 + 1) + (xcd - r8) * q8) + sidx;
  const int bm = wg / nblk, bn = wg - bm * nblk;
  const long brow = (long)bm * 256;
  const int bcol = bn * 256;

  const int t = threadIdx.x;
  const int lane = t & 63, wid = t >> 6;
  const int wr = (wid >> 2) * 128;  // 0 / 128
  const int wc = (wid & 3) * 64;    // 0,64,128,192
  const int hA = wr >> 7;
  const int hB = wc >> 7;
  const int lrB0 = wc & 127;        // 0 or 64 (row base within B half)
  const int l15 = lane & 15, l4 = lane >> 4;
  const int q0 = t * 16;

  f32x4 acc[8][4] = {};
  const int NT = K / 64;

  // prologue: stage tile 0 into buf 0
  {
    const unsigned short* Ap = A0;  // k0=0 < KA0 always
    stage_half(Ap, lda, brow, smem, q0);
    stage_half(Ap, lda, brow + 128, smem + 16384, q0);
    stage_half(BT, K, bcol, smem + 65536, q0);
    stage_half(BT, K, bcol + 128, smem + 65536 + 16384, q0);
  }
  asm volatile("s_waitcnt vmcnt(0)" ::: "memory");
  __builtin_amdgcn_s_barrier();
  __builtin_amdgcn_sched_barrier(0);

  int cur = 0;
  for (int tt = 0; tt < NT; ++tt) {
    const char* Ard = smem + cur * 32768 + hA * 16384;
    const char* Brd = smem + 65536 + cur * 32768 + hB * 16384;
    const int nk0 = (tt + 1) * 64;
    const bool has = (tt + 1 < NT);
    const unsigned short* nAp =
        has ? ((nk0 < KA0) ? A0 + nk0 : A1 + (nk0 - KA0)) : A0;
    const unsigned short* nBp = BT + (has ? nk0 : 0);
    char* Adst = smem + (cur ^ 1) * 32768;
    char* Bdst = smem + 65536 + (cur ^ 1) * 32768;

    bf16x8 bfrag[4][2];
#pragma unroll
    for (int p = 0; p < 4; ++p) {
      if (has) {
        if (p == 0) stage_half(nAp, lda, brow, Adst, q0);
        else if (p == 1) stage_half(nAp, lda, brow + 128, Adst + 16384, q0);
        else if (p == 2) stage_half(nBp, K, bcol, Bdst, q0);
        else stage_half(nBp, K, bcol + 128, Bdst + 16384, q0);
      }
      if (p == 0) {
#pragma unroll
        for (int n = 0; n < 4; ++n)
#pragma unroll
          for (int kk = 0; kk < 2; ++kk)
            bfrag[n][kk] = frag(Brd, lrB0 + n * 16 + l15, kk * 64 + l4 * 16);
      }
      bf16x8 afrag[2][2];
#pragma unroll
      for (int mm = 0; mm < 2; ++mm)
#pragma unroll
        for (int kk = 0; kk < 2; ++kk)
          afrag[mm][kk] = frag(Ard, (p * 2 + mm) * 16 + l15, kk * 64 + l4 * 16);
      __builtin_amdgcn_s_barrier();
      __builtin_amdgcn_s_setprio(1);
#pragma unroll
      for (int mm = 0; mm < 2; ++mm)
#pragma unroll
        for (int n = 0; n < 4; ++n) {
          acc[p * 2 + mm][n] = __builtin_amdgcn_mfma_f32_16x16x32_bf16(
              afrag[mm][0], bfrag[n][0], acc[p * 2 + mm][n], 0, 0, 0);
          acc[p * 2 + mm][n] = __builtin_amdgcn_mfma_f32_16x16x32_bf16(
              afrag[mm][1], bfrag[n][1], acc[p * 2 + mm][n], 0, 0, 0);
        }
      __builtin_amdgcn_s_setprio(0);
      __builtin_amdgcn_s_barrier();
    }
    // tile boundary: drain stages for next tile, then flip buffers
    asm volatile("s_waitcnt vmcnt(0)" ::: "memory");
    __builtin_amdgcn_s_barrier();
    __builtin_amdgcn_sched_barrier(0);
    cur ^= 1;
  }

  // ---------------- epilogue ----------------
  float* sstat = (float*)smem;
  if (MODE == 0) {
    sstat[t] = 0.f;
    __syncthreads();
  }

#pragma unroll
  for (int m = 0; m < 8; ++m) {
    int row0 = (int)brow + wr + m * 16 + l4 * 4;
#pragma unroll
    for (int n = 0; n < 4; ++n) {
      int col = bcol + wc + n * 16 + l15;
      if (MODE == 0) {
        float bs = bias[col];
#pragma unroll
        for (int j = 0; j < 4; ++j)
          outb[(long)(row0 + j) * ldob + col] = f2bf(acc[m][n][j] + bs);
      } else {
        if (col < 128) {
#pragma unroll
          for (int j = 0; j < 4; ++j)
            outb[(long)(row0 + j) * ldob + col] = f2bf(acc[m][n][j]);
        } else {
          int c2 = col - 128;
          if (c2 < 121) {
            float bs = bias[c2];
#pragma unroll
            for (int j = 0; j < 4; ++j) {
              int row = row0 + j;
              if (row < N_NODES) outf[(long)row * 121 + c2] = acc[m][n][j] + bs;
            }
          }
        }
      }
    }
  }

  if (MODE == 0) {
#pragma unroll
    for (int n = 0; n < 4; ++n) {
      int colL = wc + n * 16 + l15;
      float bs = bias[bcol + colL];
      float s = 0.f, s2 = 0.f;
#pragma unroll
      for (int m = 0; m < 8; ++m) {
        int row0 = (int)brow + wr + m * 16 + l4 * 4;
#pragma unroll
        for (int j = 0; j < 4; ++j) {
          if (row0 + j < N_NODES) {
            float v = acc[m][n][j] + bs;
            s += v;
            s2 += v * v;
          }
        }
      }
      atomicAdd(&sstat[colL], s);
      atomicAdd(&sstat[256 + colL], s2);
    }
    __syncthreads();
    if (t < 256) {
      atomicAdd(&ssum[bcol + t], sstat[t]);
      atomicAdd(&ssq[bcol + t], sstat[256 + t]);
    }
  }
}

// ---------------- host launcher ----------------
extern "C" void kernel_launch(void* const* d_in, const int* in_sizes, int n_in, void* d_out,
                              int out_size, void* d_ws, size_t ws_size, hipStream_t stream) {
  char* p = (char*)d_ws;
  auto take = [&](size_t b) {
    char* r = p;
    p += (b + 255) & ~(size_t)255;
    return r;
  };
  int* deg      = (int*)take((size_t)N_NODES * 4);
  int* row_ptr  = (int*)take((size_t)(N_NODES + 4) * 4);
  int* cursor   = (int*)take((size_t)N_NODES * 4);
  int* esrc     = (int*)take((size_t)N_EDGES * 4);
  int* bsum     = (int*)take(256 * 4);
  int* boffb    = (int*)take(256 * 4);
  unsigned short* W1T = (unsigned short*)take((size_t)512 * 128 * 2);
  unsigned short* W2T = (unsigned short*)take((size_t)512 * 1024 * 2);
  unsigned short* W3T = (unsigned short*)take((size_t)512 * 1024 * 2);
  unsigned short* W4T = (unsigned short*)take((size_t)256 * 512 * 2);  // [Wl4^T;Wr4^T]
  float* ssum   = (float*)take(512 * 4);
  float* ssq    = (float*)take(512 * 4);
  float* scale  = (float*)take(512 * 4);
  float* shiftv = (float*)take(512 * 4);
  unsigned short* abuf = (unsigned short*)take((size_t)M_PAD * 512 * 2);
  unsigned short* ybuf = (unsigned short*)take((size_t)M_PAD * 512 * 2);
  unsigned short* hbuf = (unsigned short*)take((size_t)M_PAD * 512 * 2);

  size_t need = (size_t)(p - (char*)d_ws);
  if (need > ws_size || n_in < 20) {
    hipMemsetAsync(d_out, 0, (size_t)out_size * 4, stream);
    return;
  }

  const float* x   = (const float*)d_in[0];
  const int*   ei  = (const int*)d_in[1];
  const int*   srcv = ei;
  const int*   dstv = ei + N_EDGES;
  const float* Wl1 = (const float*)d_in[2];
  const float* bl1 = (const float*)d_in[3];
  const float* Wr1 = (const float*)d_in[4];
  const float* Wl2 = (const float*)d_in[5];
  const float* bl2 = (const float*)d_in[6];
  const float* Wr2 = (const float*)d_in[7];
  const float* Wl3 = (const float*)d_in[8];
  const float* bl3 = (const float*)d_in[9];
  const float* Wr3 = (const float*)d_in[10];
  const float* Wl4 = (const float*)d_in[11];
  const float* bl4 = (const float*)d_in[12];
  const float* Wr4 = (const float*)d_in[13];
  const float* g1  = (const float*)d_in[14];
  const float* b1  = (const float*)d_in[15];
  const float* g2  = (const float*)d_in[16];
  const float* b2  = (const float*)d_in[17];
  const float* g3  = (const float*)d_in[18];
  const float* b3  = (const float*)d_in[19];

  // CSR (parallel scan)
  hipMemsetAsync(deg, 0, (size_t)N_NODES * 4, stream);
  count_deg<<<(N_EDGES + 255) / 256, 256, 0, stream>>>(dstv, deg);
  block_sums<<<SCAN_B, 256, 0, stream>>>(deg, bsum);
  scan_bsums<<<1, 256, 0, stream>>>(bsum, boffb);
  write_rowptr<<<SCAN_B, 256, 0, stream>>>(deg, boffb, row_ptr, cursor);
  scatter_edges<<<(N_EDGES + 255) / 256, 256, 0, stream>>>(srcv, dstv, cursor, esrc);

  // weights
  pack_wt<<<(512 * 128 + 255) / 256, 256, 0, stream>>>(Wl1, Wr1, W1T, 50, 512, 512, 128);
  pack_wt<<<(512 * 1024 + 255) / 256, 256, 0, stream>>>(Wl2, Wr2, W2T, 512, 512, 512, 1024);
  pack_wt<<<(512 * 1024 + 255) / 256, 256, 0, stream>>>(Wl3, Wr3, W3T, 512, 512, 512, 1024);
  pack_w1<<<(128 * 512 + 255) / 256, 256, 0, stream>>>(Wl4, W4T, 512, 121, 128, 512);
  pack_w1<<<(128 * 512 + 255) / 256, 256, 0, stream>>>(Wr4, W4T + 128 * 512, 512, 121, 128, 512);

  const int g23 = 196 * 2;           // 256-row panels x 2 col-blocks
  const size_t LDSB = 131072;
  int bn_blocks = (int)(((long)M_PAD * 512 / 8) / 256);

  // ---- layer 1 ----
  prep1v<<<M_PAD, 256, 0, stream>>>(x, row_ptr, esrc, abuf);
  hipMemsetAsync(ssum, 0, 4096, stream);  // ssum+ssq contiguous
  gemm256<0><<<g23, 512, LDSB, stream>>>(2, abuf, abuf, 128, 128, W1T, 128, bl1, ybuf, 512,
                                         nullptr, ssum, ssq);
  bn_finalize<<<1, 512, 0, stream>>>(ssum, ssq, g1, b1, scale, shiftv);
  bn_relu<<<bn_blocks, 256, 0, stream>>>(ybuf, scale, shiftv, hbuf);

  // ---- layer 2 ----
  agg_mean512<<<M_PAD, 256, 0, stream>>>(row_ptr, esrc, hbuf, abuf);
  hipMemsetAsync(ssum, 0, 4096, stream);
  gemm256<0><<<g23, 512, LDSB, stream>>>(2, abuf, hbuf, 512, 512, W2T, 1024, bl2, ybuf, 512,
                                         nullptr, ssum, ssq);
  bn_finalize<<<1, 512, 0, stream>>>(ssum, ssq, g2, b2, scale, shiftv);
  bn_relu<<<bn_blocks, 256, 0, stream>>>(ybuf, scale, shiftv, hbuf);

  // ---- layer 3 ----
  agg_mean512<<<M_PAD, 256, 0, stream>>>(row_ptr, esrc, hbuf, abuf);
  hipMemsetAsync(ssum, 0, 4096, stream);
  gemm256<0><<<g23, 512, LDSB, stream>>>(2, abuf, hbuf, 512, 512, W3T, 1024, bl3, ybuf, 512,
                                         nullptr, ssum, ssq);
  bn_finalize<<<1, 512, 0, stream>>>(ssum, ssq, g3, b3, scale, shiftv);
  bn_relu<<<bn_blocks, 256, 0, stream>>>(ybuf, scale, shiftv, hbuf);

  // ---- layer 4: single GEMM, split epilogue: t4=h3@Wl4 (bf16) | d_out=h3@Wr4+bl4 (f32) ----
  gemm256<1><<<196, 512, LDSB, stream>>>(1, hbuf, hbuf, 512, 512, W4T, 512, bl4, ybuf, 128,
                                         (float*)d_out, nullptr, nullptr);
  agg_add121<<<(N_NODES + 3) / 4, 256, 0, stream>>>(row_ptr, esrc, ybuf, (float*)d_out);
}

// Round 9
// 653.995 us; speedup vs baseline: 1.8917x; 1.0361x over previous
//
#include <hip/hip_runtime.h>

#define N_NODES 50000
#define N_EDGES 400000
#define M_PAD   50176   // 196 * 256
#define SCAN_B  196
#define EPS_BN  1e-5f

typedef short bf16x8 __attribute__((ext_vector_type(8)));
typedef float f32x4 __attribute__((ext_vector_type(4)));

__device__ __forceinline__ float bf2f(unsigned short h) {
  union { unsigned int u; float f; } v; v.u = ((unsigned int)h) << 16; return v.f;
}
__device__ __forceinline__ unsigned short f2bf(float x) {
  union { float f; unsigned int u; } v; v.f = x;
  unsigned int r = v.u + 0x7FFFu + ((v.u >> 16) & 1u);
  return (unsigned short)(r >> 16);
}

// ---------------- CSR build ----------------
__global__ void count_deg(const int* __restrict__ dst, int* __restrict__ deg) {
  int e = blockIdx.x * 256 + threadIdx.x;
  if (e < N_EDGES) {
    int d = dst[e];
    if (d >= 0 && d < N_NODES) atomicAdd(&deg[d], 1);
  }
}

__global__ void block_sums(const int* __restrict__ deg, int* __restrict__ bsum) {
  __shared__ int sd[256];
  int b = blockIdx.x, t = threadIdx.x;
  int i = b * 256 + t;
  sd[t] = (i < N_NODES) ? deg[i] : 0;
  __syncthreads();
  for (int off = 128; off > 0; off >>= 1) {
    if (t < off) sd[t] += sd[t + off];
    __syncthreads();
  }
  if (t == 0) bsum[b] = sd[0];
}

__global__ void scan_bsums(const int* __restrict__ bsum, int* __restrict__ boff) {
  __shared__ int sd[256];
  int t = threadIdx.x;
  int v = (t < SCAN_B) ? bsum[t] : 0;
  sd[t] = v;
  __syncthreads();
  for (int off = 1; off < 256; off <<= 1) {
    int add = (t >= off) ? sd[t - off] : 0;
    __syncthreads();
    sd[t] += add;
    __syncthreads();
  }
  if (t < SCAN_B) boff[t] = sd[t] - v;  // exclusive
}

__global__ void write_rowptr(const int* __restrict__ deg, const int* __restrict__ boff,
                             int* __restrict__ row_ptr, int* __restrict__ cursor) {
  __shared__ int sd[256];
  int b = blockIdx.x, t = threadIdx.x;
  int i = b * 256 + t;
  int v = (i < N_NODES) ? deg[i] : 0;
  sd[t] = v;
  __syncthreads();
  for (int off = 1; off < 256; off <<= 1) {
    int add = (t >= off) ? sd[t - off] : 0;
    __syncthreads();
    sd[t] += add;
    __syncthreads();
  }
  if (i < N_NODES) {
    int ex = boff[b] + sd[t] - v;
    row_ptr[i] = ex;
    cursor[i]  = ex;
    if (i == N_NODES - 1) row_ptr[N_NODES] = boff[b] + sd[t];
  }
}

__global__ void scatter_edges(const int* __restrict__ src, const int* __restrict__ dst,
                              int* __restrict__ cursor, int* __restrict__ esrc) {
  int e = blockIdx.x * 256 + threadIdx.x;
  if (e < N_EDGES) {
    int d = dst[e];
    int s = src[e];
    if (d >= 0 && d < N_NODES && s >= 0 && s < N_NODES) {
      int p = atomicAdd(&cursor[d], 1);
      esrc[p] = s;
    }
  }
}

// ---------------- weight packs ----------------
__global__ void pack_wt(const float* __restrict__ Wl, const float* __restrict__ Wr,
                        unsigned short* __restrict__ WT, int Keach, int N, int Npad, int Kpad) {
  int idx = blockIdx.x * 256 + threadIdx.x;
  if (idx >= Npad * Kpad) return;
  int n = idx / Kpad, k = idx % Kpad;
  float v = 0.f;
  if (n < N) {
    if (k < Keach) v = Wl[k * N + n];
    else if (k < 2 * Keach) v = Wr[(k - Keach) * N + n];
  }
  WT[idx] = f2bf(v);
}

__global__ void pack_w1(const float* __restrict__ W, unsigned short* __restrict__ WT, int K,
                        int N, int Npad, int Kpad) {
  int idx = blockIdx.x * 256 + threadIdx.x;
  if (idx >= Npad * Kpad) return;
  int n = idx / Kpad, k = idx % Kpad;
  float v = (n < N && k < K) ? W[k * N + n] : 0.f;
  WT[idx] = f2bf(v);
}

// ---------------- layer-1 input build ----------------
__global__ void prep1v(const float* __restrict__ x, const int* __restrict__ row_ptr,
                       const int* __restrict__ esrc, unsigned short* __restrict__ cat1) {
  __shared__ float part[4][64];
  int n = blockIdx.x, t = threadIdx.x;
  int w = t >> 6, lane = t & 63;
  unsigned short* row = cat1 + (long)n * 128;
  if (n >= N_NODES) {
    if (t < 64) { row[t] = 0; row[64 + t] = 0; }
    return;
  }
  int e0 = row_ptr[n], e1 = row_ptr[n + 1];
  float acc = 0.f;
  if (lane < 50) {
    for (int e = e0 + w; e < e1; e += 4) acc += x[(long)esrc[e] * 50 + lane];
  }
  part[w][lane] = acc;
  __syncthreads();
  if (t < 128) {
    if (t < 64) {
      float s = part[0][t] + part[1][t] + part[2][t] + part[3][t];
      float rdeg = (e1 > e0) ? 1.f / (float)(e1 - e0) : 0.f;
      if (t < 50) {
        row[t]      = f2bf(s * rdeg);
        row[50 + t] = f2bf(x[(long)n * 50 + t]);
      }
    } else if (t >= 100) {
      row[t] = 0;
    }
  }
}

// ---------------- mean aggregation, 512 cols ----------------
__global__ void agg_mean512(const int* __restrict__ row_ptr, const int* __restrict__ esrc,
                            const unsigned short* __restrict__ h,
                            unsigned short* __restrict__ agg) {
  __shared__ float part[4][512];
  int n = blockIdx.x, t = threadIdx.x;
  int w = t >> 6, lane = t & 63;
  unsigned int* outw = (unsigned int*)(agg + (long)n * 512);
  if (n >= N_NODES) { outw[t] = 0; return; }
  int e0 = row_ptr[n], e1 = row_ptr[n + 1];
  float acc[8] = {0.f, 0.f, 0.f, 0.f, 0.f, 0.f, 0.f, 0.f};
  for (int e = e0 + w; e < e1; e += 4) {
    int s = esrc[e];
    uint4 v = *(const uint4*)(h + (long)s * 512 + lane * 8);
    const unsigned short* pv = (const unsigned short*)&v;
#pragma unroll
    for (int j = 0; j < 8; ++j) acc[j] += bf2f(pv[j]);
  }
  float* pw = &part[w][lane * 8];
#pragma unroll
  for (int j = 0; j < 8; ++j) pw[j] = acc[j];
  __syncthreads();
  int c = t * 2;
  float s0 = part[0][c] + part[1][c] + part[2][c] + part[3][c];
  float s1 = part[0][c + 1] + part[1][c + 1] + part[2][c + 1] + part[3][c + 1];
  float rdeg = (e1 > e0) ? 1.f / (float)(e1 - e0) : 0.f;
  unsigned int pk = (unsigned int)f2bf(s0 * rdeg) | ((unsigned int)f2bf(s1 * rdeg) << 16);
  outw[t] = pk;
}

// ---------------- layer-4 gather-add, 121 cols ----------------
__global__ void agg_add121(const int* __restrict__ row_ptr, const int* __restrict__ esrc,
                           const unsigned short* __restrict__ t4, float* __restrict__ out) {
  int n = blockIdx.x * 4 + (threadIdx.x >> 6);
  if (n >= N_NODES) return;
  int lane = threadIdx.x & 63;
  int g = lane >> 4;
  int cl = lane & 15;
  int e0 = row_ptr[n], e1 = row_ptr[n + 1];
  float acc[8] = {0.f, 0.f, 0.f, 0.f, 0.f, 0.f, 0.f, 0.f};
  for (int e = e0 + g; e < e1; e += 4) {
    int s = esrc[e];
    uint4 v = *(const uint4*)(t4 + (long)s * 128 + cl * 8);
    const unsigned short* pv = (const unsigned short*)&v;
#pragma unroll
    for (int j = 0; j < 8; ++j) acc[j] += bf2f(pv[j]);
  }
#pragma unroll
  for (int j = 0; j < 8; ++j) {
    acc[j] += __shfl_xor(acc[j], 16);
    acc[j] += __shfl_xor(acc[j], 32);
  }
  if (g == 0) {
    float rdeg = (e1 > e0) ? 1.f / (float)(e1 - e0) : 0.f;
#pragma unroll
    for (int j = 0; j < 8; ++j) {
      int c = cl * 8 + j;
      if (c < 121) out[(long)n * 121 + c] += acc[j] * rdeg;
    }
  }
}

// ---------------- BN finalize / apply+ReLU ----------------
__global__ void bn_finalize(const float* __restrict__ ssum, const float* __restrict__ ssq,
                            const float* __restrict__ g, const float* __restrict__ b,
                            float* __restrict__ scale, float* __restrict__ shiftv) {
  int c = threadIdx.x;
  float mu  = ssum[c] * (1.f / N_NODES);
  float var = ssq[c] * (1.f / N_NODES) - mu * mu;
  float rs  = rsqrtf(var + EPS_BN);
  float sc  = g[c] * rs;
  scale[c]  = sc;
  shiftv[c] = b[c] - mu * sc;
}

__global__ void bn_relu(const unsigned short* __restrict__ y, const float* __restrict__ scale,
                        const float* __restrict__ shiftv, unsigned short* __restrict__ hout) {
  long idx = ((long)blockIdx.x * 256 + threadIdx.x) * 8;
  if (idx >= (long)M_PAD * 512) return;
  int row = (int)(idx >> 9);
  int col = (int)(idx & 511);
  unsigned short* o = hout + idx;
  if (row >= N_NODES) {
    uint4 z; z.x = 0; z.y = 0; z.z = 0; z.w = 0;
    *(uint4*)o = z;
    return;
  }
  uint4 v = *(const uint4*)(y + idx);
  unsigned short* p = (unsigned short*)&v;
  uint4 rr;
  unsigned short* q = (unsigned short*)&rr;
#pragma unroll
  for (int j = 0; j < 8; ++j) {
    float f = bf2f(p[j]) * scale[col + j] + shiftv[col + j];
    q[j] = f2bf(fmaxf(f, 0.f));
  }
  *(uint4*)o = rr;
}

// ---------------- 256x256 bf16 MFMA GEMM, relaxed schedule ----------------
// A row-major [M][lda] in two column-halves (A0: k<KA0, A1: k>=KA0); B as BT[N][K].
// 8 waves (2M x 4N), per-wave C = 128x64. LDS 128KB dynamic dbuf. T2 XOR-swizzle.
// Schedule: per K-tile: issue ALL next-tile stages first (async), compute whole tile
// barrier-free, then one vmcnt(0)+s_barrier at the boundary.
__device__ __forceinline__ void gl_lds16(const void* g, void* l) {
  __builtin_amdgcn_global_load_lds((const __attribute__((address_space(1))) unsigned int*)g,
                                   (__attribute__((address_space(3))) unsigned int*)l, 16, 0, 0);
}

__device__ __forceinline__ void stage_half(const unsigned short* srck, int ld, long row0,
                                           char* ldshalf, int q0) {
#pragma unroll
  for (int r = 0; r < 2; ++r) {
    int q = q0 + r * 8192;
    int row = q >> 7;
    int cus = ((q & 127) >> 1) ^ ((row & 7) << 3);  // inverse-swizzled source col (ushort)
    gl_lds16(srck + (row0 + row) * (long)ld + cus, ldshalf + q);
  }
}

__device__ __forceinline__ bf16x8 frag(const char* halfbase, int lr, int cb) {
  return *(const bf16x8*)(halfbase + lr * 128 + (cb ^ ((lr & 7) << 4)));
}

template <int MODE>
__launch_bounds__(512, 2)
__global__ void gemm256(int nblk, const unsigned short* __restrict__ A0,
                        const unsigned short* __restrict__ A1, int lda, int KA0,
                        const unsigned short* __restrict__ BT, int K,
                        const float* __restrict__ bias, unsigned short* __restrict__ outb,
                        int ldob, float* __restrict__ outf, float* __restrict__ ssum,
                        float* __restrict__ ssq) {
  extern __shared__ char smem[];

  // T1: bijective XCD-chunk swizzle
  const int nwg = gridDim.x, orig = blockIdx.x;
  const int xcd = orig & 7, sidx = orig >> 3;
  const int q8 = nwg >> 3, r8 = nwg & 7;
  const int wg = ((xcd < r8) ? xcd * (q8 + 1) : r8 * (q8 + 1) + (xcd - r8) * q8) + sidx;
  const int bm = wg / nblk, bn = wg - bm * nblk;
  const long brow = (long)bm * 256;
  const int bcol = bn * 256;

  const int t = threadIdx.x;
  const int lane = t & 63, wid = t >> 6;
  const int wr = (wid >> 2) * 128;  // 0 / 128
  const int wc = (wid & 3) * 64;    // 0,64,128,192
  const int hA = wr >> 7;
  const int hB = wc >> 7;
  const int lrB0 = wc & 127;        // 0 or 64 (row base within B half)
  const int l15 = lane & 15, l4 = lane >> 4;
  const int q0 = t * 16;

  f32x4 acc[8][4] = {};
  const int NT = K / 64;

  // prologue: stage tile 0 into buf 0
  {
    const unsigned short* Ap = A0;  // k0=0 < KA0 always
    stage_half(Ap, lda, brow, smem, q0);
    stage_half(Ap, lda, brow + 128, smem + 16384, q0);
    stage_half(BT, K, bcol, smem + 65536, q0);
    stage_half(BT, K, bcol + 128, smem + 65536 + 16384, q0);
  }
  asm volatile("s_waitcnt vmcnt(0)" ::: "memory");
  __builtin_amdgcn_s_barrier();

  int cur = 0;
  for (int tt = 0; tt < NT; ++tt) {
    // issue next-tile stages FIRST (async; whole tile of compute hides their latency)
    if (tt + 1 < NT) {
      const int nk0 = (tt + 1) * 64;
      const unsigned short* nAp = (nk0 < KA0) ? A0 + nk0 : A1 + (nk0 - KA0);
      const unsigned short* nBp = BT + nk0;
      char* Adst = smem + (cur ^ 1) * 32768;
      char* Bdst = smem + 65536 + (cur ^ 1) * 32768;
      stage_half(nAp, lda, brow, Adst, q0);
      stage_half(nAp, lda, brow + 128, Adst + 16384, q0);
      stage_half(nBp, K, bcol, Bdst, q0);
      stage_half(nBp, K, bcol + 128, Bdst + 16384, q0);
    }

    const char* Ard = smem + cur * 32768 + hA * 16384;
    const char* Brd = smem + 65536 + cur * 32768 + hB * 16384;

    bf16x8 bfrag[4][2];
#pragma unroll
    for (int n = 0; n < 4; ++n)
#pragma unroll
      for (int kk = 0; kk < 2; ++kk)
        bfrag[n][kk] = frag(Brd, lrB0 + n * 16 + l15, kk * 64 + l4 * 16);

#pragma unroll
    for (int p = 0; p < 4; ++p) {
      bf16x8 afrag[2][2];
#pragma unroll
      for (int mm = 0; mm < 2; ++mm)
#pragma unroll
        for (int kk = 0; kk < 2; ++kk)
          afrag[mm][kk] = frag(Ard, (p * 2 + mm) * 16 + l15, kk * 64 + l4 * 16);
#pragma unroll
      for (int mm = 0; mm < 2; ++mm)
#pragma unroll
        for (int n = 0; n < 4; ++n) {
          acc[p * 2 + mm][n] = __builtin_amdgcn_mfma_f32_16x16x32_bf16(
              afrag[mm][0], bfrag[n][0], acc[p * 2 + mm][n], 0, 0, 0);
          acc[p * 2 + mm][n] = __builtin_amdgcn_mfma_f32_16x16x32_bf16(
              afrag[mm][1], bfrag[n][1], acc[p * 2 + mm][n], 0, 0, 0);
        }
    }

    // single sync per tile: drain stages, flip buffers
    asm volatile("s_waitcnt vmcnt(0)" ::: "memory");
    __builtin_amdgcn_s_barrier();
    cur ^= 1;
  }

  // ---------------- epilogue ----------------
  float* sstat = (float*)smem;
  if (MODE == 0) {
    sstat[t] = 0.f;
    __syncthreads();
  }

#pragma unroll
  for (int m = 0; m < 8; ++m) {
    int row0 = (int)brow + wr + m * 16 + l4 * 4;
#pragma unroll
    for (int n = 0; n < 4; ++n) {
      int col = bcol + wc + n * 16 + l15;
      if (MODE == 0) {
        float bs = bias[col];
#pragma unroll
        for (int j = 0; j < 4; ++j)
          outb[(long)(row0 + j) * ldob + col] = f2bf(acc[m][n][j] + bs);
      } else {
        if (col < 128) {
#pragma unroll
          for (int j = 0; j < 4; ++j)
            outb[(long)(row0 + j) * ldob + col] = f2bf(acc[m][n][j]);
        } else {
          int c2 = col - 128;
          if (c2 < 121) {
            float bs = bias[c2];
#pragma unroll
            for (int j = 0; j < 4; ++j) {
              int row = row0 + j;
              if (row < N_NODES) outf[(long)row * 121 + c2] = acc[m][n][j] + bs;
            }
          }
        }
      }
    }
  }

  if (MODE == 0) {
#pragma unroll
    for (int n = 0; n < 4; ++n) {
      int colL = wc + n * 16 + l15;
      float bs = bias[bcol + colL];
      float s = 0.f, s2 = 0.f;
#pragma unroll
      for (int m = 0; m < 8; ++m) {
        int row0 = (int)brow + wr + m * 16 + l4 * 4;
#pragma unroll
        for (int j = 0; j < 4; ++j) {
          if (row0 + j < N_NODES) {
            float v = acc[m][n][j] + bs;
            s += v;
            s2 += v * v;
          }
        }
      }
      atomicAdd(&sstat[colL], s);
      atomicAdd(&sstat[256 + colL], s2);
    }
    __syncthreads();
    if (t < 256) {
      atomicAdd(&ssum[bcol + t], sstat[t]);
      atomicAdd(&ssq[bcol + t], sstat[256 + t]);
    }
  }
}

// ---------------- host launcher ----------------
extern "C" void kernel_launch(void* const* d_in, const int* in_sizes, int n_in, void* d_out,
                              int out_size, void* d_ws, size_t ws_size, hipStream_t stream) {
  char* p = (char*)d_ws;
  auto take = [&](size_t b) {
    char* r = p;
    p += (b + 255) & ~(size_t)255;
    return r;
  };
  int* deg      = (int*)take((size_t)N_NODES * 4);
  int* row_ptr  = (int*)take((size_t)(N_NODES + 4) * 4);
  int* cursor   = (int*)take((size_t)N_NODES * 4);
  int* esrc     = (int*)take((size_t)N_EDGES * 4);
  int* bsum     = (int*)take(256 * 4);
  int* boffb    = (int*)take(256 * 4);
  unsigned short* W1T = (unsigned short*)take((size_t)512 * 128 * 2);
  unsigned short* W2T = (unsigned short*)take((size_t)512 * 1024 * 2);
  unsigned short* W3T = (unsigned short*)take((size_t)512 * 1024 * 2);
  unsigned short* W4T = (unsigned short*)take((size_t)256 * 512 * 2);  // [Wl4^T;Wr4^T]
  float* ssum   = (float*)take(512 * 4);
  float* ssq    = (float*)take(512 * 4);
  float* scale  = (float*)take(512 * 4);
  float* shiftv = (float*)take(512 * 4);
  unsigned short* abuf = (unsigned short*)take((size_t)M_PAD * 512 * 2);
  unsigned short* ybuf = (unsigned short*)take((size_t)M_PAD * 512 * 2);
  unsigned short* hbuf = (unsigned short*)take((size_t)M_PAD * 512 * 2);

  size_t need = (size_t)(p - (char*)d_ws);
  if (need > ws_size || n_in < 20) {
    hipMemsetAsync(d_out, 0, (size_t)out_size * 4, stream);
    return;
  }

  const float* x   = (const float*)d_in[0];
  const int*   ei  = (const int*)d_in[1];
  const int*   srcv = ei;
  const int*   dstv = ei + N_EDGES;
  const float* Wl1 = (const float*)d_in[2];
  const float* bl1 = (const float*)d_in[3];
  const float* Wr1 = (const float*)d_in[4];
  const float* Wl2 = (const float*)d_in[5];
  const float* bl2 = (const float*)d_in[6];
  const float* Wr2 = (const float*)d_in[7];
  const float* Wl3 = (const float*)d_in[8];
  const float* bl3 = (const float*)d_in[9];
  const float* Wr3 = (const float*)d_in[10];
  const float* Wl4 = (const float*)d_in[11];
  const float* bl4 = (const float*)d_in[12];
  const float* Wr4 = (const float*)d_in[13];
  const float* g1  = (const float*)d_in[14];
  const float* b1  = (const float*)d_in[15];
  const float* g2  = (const float*)d_in[16];
  const float* b2  = (const float*)d_in[17];
  const float* g3  = (const float*)d_in[18];
  const float* b3  = (const float*)d_in[19];

  // CSR (parallel scan)
  hipMemsetAsync(deg, 0, (size_t)N_NODES * 4, stream);
  count_deg<<<(N_EDGES + 255) / 256, 256, 0, stream>>>(dstv, deg);
  block_sums<<<SCAN_B, 256, 0, stream>>>(deg, bsum);
  scan_bsums<<<1, 256, 0, stream>>>(bsum, boffb);
  write_rowptr<<<SCAN_B, 256, 0, stream>>>(deg, boffb, row_ptr, cursor);
  scatter_edges<<<(N_EDGES + 255) / 256, 256, 0, stream>>>(srcv, dstv, cursor, esrc);

  // weights
  pack_wt<<<(512 * 128 + 255) / 256, 256, 0, stream>>>(Wl1, Wr1, W1T, 50, 512, 512, 128);
  pack_wt<<<(512 * 1024 + 255) / 256, 256, 0, stream>>>(Wl2, Wr2, W2T, 512, 512, 512, 1024);
  pack_wt<<<(512 * 1024 + 255) / 256, 256, 0, stream>>>(Wl3, Wr3, W3T, 512, 512, 512, 1024);
  pack_w1<<<(128 * 512 + 255) / 256, 256, 0, stream>>>(Wl4, W4T, 512, 121, 128, 512);
  pack_w1<<<(128 * 512 + 255) / 256, 256, 0, stream>>>(Wr4, W4T + 128 * 512, 512, 121, 128, 512);

  const int g23 = 196 * 2;           // 256-row panels x 2 col-blocks
  const size_t LDSB = 131072;
  int bn_blocks = (int)(((long)M_PAD * 512 / 8) / 256);

  // ---- layer 1 ----
  prep1v<<<M_PAD, 256, 0, stream>>>(x, row_ptr, esrc, abuf);
  hipMemsetAsync(ssum, 0, 4096, stream);  // ssum+ssq contiguous
  gemm256<0><<<g23, 512, LDSB, stream>>>(2, abuf, abuf, 128, 128, W1T, 128, bl1, ybuf, 512,
                                         nullptr, ssum, ssq);
  bn_finalize<<<1, 512, 0, stream>>>(ssum, ssq, g1, b1, scale, shiftv);
  bn_relu<<<bn_blocks, 256, 0, stream>>>(ybuf, scale, shiftv, hbuf);

  // ---- layer 2 ----
  agg_mean512<<<M_PAD, 256, 0, stream>>>(row_ptr, esrc, hbuf, abuf);
  hipMemsetAsync(ssum, 0, 4096, stream);
  gemm256<0><<<g23, 512, LDSB, stream>>>(2, abuf, hbuf, 512, 512, W2T, 1024, bl2, ybuf, 512,
                                         nullptr, ssum, ssq);
  bn_finalize<<<1, 512, 0, stream>>>(ssum, ssq, g2, b2, scale, shiftv);
  bn_relu<<<bn_blocks, 256, 0, stream>>>(ybuf, scale, shiftv, hbuf);

  // ---- layer 3 ----
  agg_mean512<<<M_PAD, 256, 0, stream>>>(row_ptr, esrc, hbuf, abuf);
  hipMemsetAsync(ssum, 0, 4096, stream);
  gemm256<0><<<g23, 512, LDSB, stream>>>(2, abuf, hbuf, 512, 512, W3T, 1024, bl3, ybuf, 512,
                                         nullptr, ssum, ssq);
  bn_finalize<<<1, 512, 0, stream>>>(ssum, ssq, g3, b3, scale, shiftv);
  bn_relu<<<bn_blocks, 256, 0, stream>>>(ybuf, scale, shiftv, hbuf);

  // ---- layer 4: single GEMM, split epilogue: t4=h3@Wl4 (bf16) | d_out=h3@Wr4+bl4 (f32) ----
  gemm256<1><<<196, 512, LDSB, stream>>>(1, hbuf, hbuf, 512, 512, W4T, 512, bl4, ybuf, 128,
                                         (float*)d_out, nullptr, nullptr);
  agg_add121<<<(N_NODES + 3) / 4, 256, 0, stream>>>(row_ptr, esrc, ybuf, (float*)d_out);
}